// Round 3
// baseline (104948.389 us; speedup 1.0000x reference)
//
#include <hip/hip_runtime.h>
#include <hip/hip_bf16.h>
#include <math.h>
#include <stdint.h>

// Seq2Seq LAS model. B=32, T=1664, F_IN=80, H_ENC=256, KV=128, D_DEC=512,
// EMB=256, VOCAB=30, L=200.
// Encoder: persistent biLSTM kernels (64 WGs = 32/dir), per-step sync via
// RELAXED agent-scope atomics only (no threadfence -> no buffer_wbl2/inv L2
// flush storms; that was R2's 29us/step overhead). h exchange is coherent
// (sc0 sc1) loads/stores; __syncthreads' vmcnt(0) drain provides ordering.
// Input projections folded into the recurrent dot (weights in registers).
// Decoder: 200 steps x 3 small kernels.

#define DEV __device__ __forceinline__

DEV float sigmf(float x) { return 1.0f / (1.0f + __expf(-x)); }
DEV float tanh_(float x) { return 1.0f - 2.0f / (__expf(2.0f * x) + 1.0f); }

struct __align__(8) bf4 { __hip_bfloat16 a, b, c, d; };

DEV float4 ld4g(const float* p) { return *(const float4*)p; }
DEV float4 ld4g(const __hip_bfloat16* p) {
    bf4 v = *(const bf4*)p;
    return make_float4(__bfloat162float(v.a), __bfloat162float(v.b),
                       __bfloat162float(v.c), __bfloat162float(v.d));
}
DEV void st1g(float* p, float v) { *p = v; }
DEV void st1g(__hip_bfloat16* p, float v) { *p = __float2bfloat16(v); }

DEV float ld_coh(float* p) {
    return __hip_atomic_load(p, __ATOMIC_RELAXED, __HIP_MEMORY_SCOPE_AGENT);
}
DEV void st_coh(float* p, float v) {
    __hip_atomic_store(p, v, __ATOMIC_RELAXED, __HIP_MEMORY_SCOPE_AGENT);
}

// ---------------------------------------------------------------------------
// step barrier among 32 WGs of one direction. Fence-free: h was stored with
// coherent stores; __syncthreads drains vmcnt so they are globally visible
// before the flag store. Readers poll with coherent loads (bypass L1/L2).
// ---------------------------------------------------------------------------
DEV void step_barrier(unsigned* myflags, int w, int tid, unsigned tv)
{
    __syncthreads();  // s_waitcnt vmcnt(0): my coherent h-stores are visible
    if (tid == 0)
        __hip_atomic_store(&myflags[w], tv, __ATOMIC_RELAXED,
                           __HIP_MEMORY_SCOPE_AGENT);
    if (tid < 32) {
        int guard = 0;
        while (__hip_atomic_load(&myflags[tid], __ATOMIC_RELAXED,
                                 __HIP_MEMORY_SCOPE_AGENT) < tv) {
            __builtin_amdgcn_s_sleep(1);
            if (++guard > (1 << 15)) break;  // anti-hang: fail loud, not forever
        }
    }
    __syncthreads();
}

// ---------------------------------------------------------------------------
// Encoder layer 0 (persistent). K = 256 h + 80 x + 16 pad = 352.
// grid 64x256: dir = blk>>5, w = blk&31 (owns hidden units w*8..w*8+8).
// hbuf: [dir][parity][b][256] (b-major); flags: [dir][32].
// ---------------------------------------------------------------------------
template <typename ST>
__global__ __launch_bounds__(256, 1) void lstm_l0(
    const float* __restrict__ x,        // [32][1664][80]
    const float* __restrict__ whh_f, const float* __restrict__ whh_b,  // [1024][256]
    const float* __restrict__ wih_f, const float* __restrict__ wih_b,  // [1024][80]
    const float* __restrict__ bias_f, const float* __restrict__ bias_b,
    ST* __restrict__ out,               // [32][1664][512]
    float* __restrict__ hbuf, unsigned* __restrict__ flags)
{
    const int T = 1664;
    const int KK = 352;
    __shared__ __align__(16) float hs[32 * 352];
    __shared__ __align__(16) float pb[4096];

    const int tid = threadIdx.x;
    const int dir = blockIdx.x >> 5;
    const int w = blockIdx.x & 31;
    const int wave = tid >> 6, lane = tid & 63;
    const int colL = lane & 31, ksub = lane >> 5;
    const int kbase = (wave * 2 + ksub) * 44;
    const int col = (colL >> 3) * 256 + w * 8 + (colL & 7);

    const float* Whh = dir ? whh_b : whh_f;
    const float* Wih = dir ? wih_b : wih_f;
    const float* bias = dir ? bias_b : bias_f;

    float wreg[44];
#pragma unroll
    for (int i = 0; i < 44; i++) {
        int k = kbase + i;
        float v = 0.f;
        if (k < 256) v = Whh[col * 256 + k];
        else if (k < 336) v = Wih[col * 80 + (k - 256)];
        wreg[i] = v;
    }

    const int ub = tid >> 3, uj = tid & 7;
    const int uhid = w * 8 + uj;
    float c_reg = 0.f;
    unsigned* myflags = flags + dir * 32;
    float* hb_base = hbuf + dir * 2 * 8192;

    // zero the 16-wide K pad once
    for (int i = tid; i < 512; i += 256)
        hs[(i >> 4) * KK + 336 + (i & 15)] = 0.f;

    for (int t = 0; t < T; t++) {
        const int par = t & 1;
        const int t_act = dir ? (T - 1 - t) : t;

        // stage h_prev (coherent, identity layout) and x_t
        float* hin = hb_base + par * 8192;
        for (int i = tid; i < 8192; i += 256)
            hs[(i >> 8) * KK + (i & 255)] = ld_coh(&hin[i]);
        for (int i4 = tid; i4 < 640; i4 += 256) {
            int e = i4 * 4;
            int bb = e / 80, jj = e % 80;
            float4 v = *(const float4*)&x[((size_t)bb * 1664 + t_act) * 80 + jj];
            *(float4*)&hs[bb * KK + 256 + jj] = v;
        }
        __syncthreads();

        float acc[32];
#pragma unroll
        for (int b = 0; b < 32; b++) acc[b] = 0.f;
#pragma unroll
        for (int q = 0; q < 11; q++) {
            float w0 = wreg[q * 4 + 0], w1 = wreg[q * 4 + 1];
            float w2 = wreg[q * 4 + 2], w3 = wreg[q * 4 + 3];
#pragma unroll
            for (int b = 0; b < 32; b++) {
                float4 hv = *(const float4*)&hs[b * KK + kbase + q * 4];
                acc[b] = fmaf(hv.x, w0, fmaf(hv.y, w1, fmaf(hv.z, w2, fmaf(hv.w, w3, acc[b]))));
            }
        }
#pragma unroll
        for (int b = 0; b < 32; b++) acc[b] += __shfl_xor(acc[b], 32, 64);
        if (ksub == 0) {
#pragma unroll
            for (int b = 0; b < 32; b++) pb[(wave * 32 + b) * 32 + colL] = acc[b];
        }
        __syncthreads();

        float gv[4];
#pragma unroll
        for (int g = 0; g < 4; g++) {
            int cl = g * 8 + uj;
            float s = bias[g * 256 + uhid];
#pragma unroll
            for (int v = 0; v < 4; v++) s += pb[(v * 32 + ub) * 32 + cl];
            gv[g] = s;
        }
        float ci = sigmf(gv[0]), cf = sigmf(gv[1]);
        float cg = tanh_(gv[2]), co = sigmf(gv[3]);
        c_reg = cf * c_reg + ci * cg;
        float hval = co * tanh_(c_reg);

        st_coh(&hb_base[(par ^ 1) * 8192 + ub * 256 + uhid], hval);
        st1g(&out[((size_t)ub * T + t_act) * 512 + dir * 256 + uhid], hval);

        step_barrier(myflags, w, tid, (unsigned)(t + 1));
    }
}

// ---------------------------------------------------------------------------
// Pyramid layer (persistent). Input = concat pair of prev frames (K_in=1024),
// folded into the dot: K = 256 h + 1024 in, processed as 5 LDS chunks of 256.
// wreg4[5][8]: chunk 0 = Whh slice, chunks 1-4 = Wih slices. in/out are ST.
// ---------------------------------------------------------------------------
template <typename ST>
__global__ __launch_bounds__(256, 1) void lstm_pyr(
    const ST* __restrict__ in,          // [32][2*Tn][512]
    const float* __restrict__ whh_f, const float* __restrict__ whh_b,  // [1024][256]
    const float* __restrict__ wih_f, const float* __restrict__ wih_b,  // [1024][1024]
    const float* __restrict__ bias_f, const float* __restrict__ bias_b,
    ST* __restrict__ out,               // [32][Tn][512]
    float* __restrict__ hbuf, unsigned* __restrict__ flags, int Tn)
{
    __shared__ __align__(16) float hs[32 * 256];
    __shared__ __align__(16) float pb[4096];

    const int tid = threadIdx.x;
    const int dir = blockIdx.x >> 5;
    const int w = blockIdx.x & 31;
    const int wave = tid >> 6, lane = tid & 63;
    const int colL = lane & 31, ksub = lane >> 5;
    const int ks = (wave * 2 + ksub) * 32;   // k-slice within each 256-chunk
    const int col = (colL >> 3) * 256 + w * 8 + (colL & 7);
    const int Tprev = 2 * Tn;

    const float* Whh = dir ? whh_b : whh_f;
    const float* Wih = dir ? wih_b : wih_f;
    const float* bias = dir ? bias_b : bias_f;

    float4 wreg4[40];
#pragma unroll
    for (int c = 0; c < 5; c++)
#pragma unroll
        for (int q = 0; q < 8; q++)
            wreg4[c * 8 + q] = (c == 0)
                ? *(const float4*)&Whh[(size_t)col * 256 + ks + q * 4]
                : *(const float4*)&Wih[(size_t)col * 1024 + (c - 1) * 256 + ks + q * 4];

    const int ub = tid >> 3, uj = tid & 7;
    const int uhid = w * 8 + uj;
    float c_reg = 0.f;
    unsigned* myflags = flags + dir * 32;
    float* hb_base = hbuf + dir * 2 * 8192;

    for (int t = 0; t < Tn; t++) {
        const int par = t & 1;
        const int t_act = dir ? (Tn - 1 - t) : t;

        float acc[32];
#pragma unroll
        for (int b = 0; b < 32; b++) acc[b] = 0.f;

        // ---- chunk 0: h_prev (coherent identity copy to LDS) ----
        float* hin = hb_base + par * 8192;
        for (int i = tid; i < 8192; i += 256)
            hs[i] = ld_coh(&hin[i]);
        __syncthreads();
#pragma unroll
        for (int q = 0; q < 8; q++) {
            float4 wv = wreg4[q];
#pragma unroll
            for (int b = 0; b < 32; b++) {
                float4 hv = *(const float4*)&hs[b * 256 + ks + q * 4];
                acc[b] = fmaf(hv.x, wv.x, fmaf(hv.y, wv.y, fmaf(hv.z, wv.z, fmaf(hv.w, wv.w, acc[b]))));
            }
        }

        // ---- chunks 1..4: input pair rows (2t, 2t+1) x (lo, hi 256) ----
        for (int c = 1; c <= 4; c++) {
            int r = 2 * t_act + ((c - 1) >> 1);
            int cb = ((c - 1) & 1) * 256;
            __syncthreads();  // everyone done with previous chunk
#pragma unroll
            for (int i4 = 0; i4 < 8; i4++) {
                int e = (tid + i4 * 256) * 4;
                int bb = e >> 8, jj = e & 255;
                float4 v = ld4g(&in[((size_t)bb * Tprev + r) * 512 + cb + jj]);
                *(float4*)&hs[bb * 256 + jj] = v;
            }
            __syncthreads();
#pragma unroll
            for (int q = 0; q < 8; q++) {
                float4 wv = wreg4[c * 8 + q];
#pragma unroll
                for (int b = 0; b < 32; b++) {
                    float4 hv = *(const float4*)&hs[b * 256 + ks + q * 4];
                    acc[b] = fmaf(hv.x, wv.x, fmaf(hv.y, wv.y, fmaf(hv.z, wv.z, fmaf(hv.w, wv.w, acc[b]))));
                }
            }
        }

#pragma unroll
        for (int b = 0; b < 32; b++) acc[b] += __shfl_xor(acc[b], 32, 64);
        if (ksub == 0) {
#pragma unroll
            for (int b = 0; b < 32; b++) pb[(wave * 32 + b) * 32 + colL] = acc[b];
        }
        __syncthreads();

        float gv[4];
#pragma unroll
        for (int g = 0; g < 4; g++) {
            int cl = g * 8 + uj;
            float s = bias[g * 256 + uhid];
#pragma unroll
            for (int v = 0; v < 4; v++) s += pb[(v * 32 + ub) * 32 + cl];
            gv[g] = s;
        }
        float ci = sigmf(gv[0]), cf = sigmf(gv[1]);
        float cg = tanh_(gv[2]), co = sigmf(gv[3]);
        c_reg = cf * c_reg + ci * cg;
        float hval = co * tanh_(c_reg);

        st_coh(&hb_base[(par ^ 1) * 8192 + ub * 256 + uhid], hval);
        st1g(&out[((size_t)ub * Tn + t_act) * 512 + dir * 256 + uhid], hval);

        step_barrier(myflags, w, tid, (unsigned)(t + 1));
    }
}

// ---------------------------------------------------------------------------
// C[M][N] = A[M][K] @ W[N][K]^T + bias  (fp32, 128x128 tiles, 8x8/thread)
// ---------------------------------------------------------------------------
__global__ __launch_bounds__(256) void gemm_bt(
    const float* __restrict__ A, const float* __restrict__ W,
    const float* __restrict__ bias, float* __restrict__ C,
    int M, int N, int K, int ldw)
{
    __shared__ __align__(16) float As[16][128];
    __shared__ __align__(16) float Ws[16][128];
    int tid = threadIdx.x;
    int m0 = blockIdx.x * 128, n0 = blockIdx.y * 128;
    int tx = tid & 15, ty = tid >> 4;

    float acc[8][8];
#pragma unroll
    for (int i = 0; i < 8; i++)
#pragma unroll
        for (int j = 0; j < 8; j++) acc[i][j] = 0.f;

    for (int kb = 0; kb < K; kb += 16) {
#pragma unroll
        for (int l = 0; l < 2; l++) {
            int idx = tid + l * 256;
            int row = idx >> 2, kq = (idx & 3) * 4;
            float4 v = make_float4(0.f, 0.f, 0.f, 0.f);
            if (m0 + row < M)
                v = *(const float4*)&A[(size_t)(m0 + row) * K + kb + kq];
            As[kq + 0][row] = v.x; As[kq + 1][row] = v.y;
            As[kq + 2][row] = v.z; As[kq + 3][row] = v.w;
        }
#pragma unroll
        for (int l = 0; l < 2; l++) {
            int idx = tid + l * 256;
            int row = idx >> 2, kq = (idx & 3) * 4;
            float4 v = *(const float4*)&W[(size_t)(n0 + row) * ldw + kb + kq];
            Ws[kq + 0][row] = v.x; Ws[kq + 1][row] = v.y;
            Ws[kq + 2][row] = v.z; Ws[kq + 3][row] = v.w;
        }
        __syncthreads();
#pragma unroll
        for (int k = 0; k < 16; k++) {
            float a[8], b[8];
            *(float4*)&a[0] = *(const float4*)&As[k][ty * 8];
            *(float4*)&a[4] = *(const float4*)&As[k][ty * 8 + 4];
            *(float4*)&b[0] = *(const float4*)&Ws[k][tx * 8];
            *(float4*)&b[4] = *(const float4*)&Ws[k][tx * 8 + 4];
#pragma unroll
            for (int i = 0; i < 8; i++)
#pragma unroll
                for (int j = 0; j < 8; j++)
                    acc[i][j] = fmaf(a[i], b[j], acc[i][j]);
        }
        __syncthreads();
    }
#pragma unroll
    for (int i = 0; i < 8; i++) {
        int m = m0 + ty * 8 + i;
        if (m >= M) continue;
#pragma unroll
        for (int j = 0; j < 8; j++)
            C[(size_t)m * N + n0 + tx * 8 + j] = acc[i][j] + bias[n0 + tx * 8 + j];
    }
}

__global__ void bf16_to_f32(const __hip_bfloat16* __restrict__ in,
                            float* __restrict__ out, int n)
{
    int i = blockIdx.x * 256 + threadIdx.x;
    if (i < n) out[i] = __bfloat162float(in[i]);
}

// ---------------------------------------------------------------------------
// ctx0 = mean over s of val[b][s][k] -> ctxT [128][32]
// ---------------------------------------------------------------------------
__global__ void ctx0_kernel(const float* __restrict__ val, float* __restrict__ ctxT)
{
    int gid = blockIdx.x * 256 + threadIdx.x;
    if (gid >= 4096) return;
    int k = gid >> 5, b = gid & 31;
    float s = 0.f;
    for (int t = 0; t < 208; t++) s += val[((size_t)b * 208 + t) * 128 + k];
    ctxT[k * 32 + b] = s * (1.0f / 208.0f);
}

// ---------------------------------------------------------------------------
// Decoder cell 1. thread = (h = gid>>5 in [0,512), b = gid&31)
// ---------------------------------------------------------------------------
__global__ __launch_bounds__(256) void dec_cell1(
    const float* __restrict__ table,   // [30][2048] = emb@Wih[:, :256]^T + d1_b
    const int* __restrict__ y,         // [32][200]
    const float* __restrict__ Wih,     // [2048][384]
    const float* __restrict__ Whh,     // [2048][512]
    const float* __restrict__ ctxT_in, // [128][32]
    const float* __restrict__ h1T_in,  // [512][32]
    float* __restrict__ h1T_out,
    float* __restrict__ c1T,
    int t)
{
    int gid = blockIdx.x * 256 + threadIdx.x;
    int h = gid >> 5, b = gid & 31;
    int tok = (t == 0) ? 0 : y[b * 200 + t - 1];

    float acc[4];
#pragma unroll
    for (int g = 0; g < 4; g++) acc[g] = table[tok * 2048 + g * 512 + h];

#pragma unroll 2
    for (int q = 0; q < 32; q++) {
        float hv0 = ctxT_in[(q * 4 + 0) * 32 + b];
        float hv1 = ctxT_in[(q * 4 + 1) * 32 + b];
        float hv2 = ctxT_in[(q * 4 + 2) * 32 + b];
        float hv3 = ctxT_in[(q * 4 + 3) * 32 + b];
#pragma unroll
        for (int g = 0; g < 4; g++) {
            float4 w4 = *(const float4*)&Wih[(size_t)(g * 512 + h) * 384 + 256 + q * 4];
            acc[g] = fmaf(hv0, w4.x, fmaf(hv1, w4.y, fmaf(hv2, w4.z, fmaf(hv3, w4.w, acc[g]))));
        }
    }
#pragma unroll 2
    for (int q = 0; q < 128; q++) {
        float hv0 = h1T_in[(q * 4 + 0) * 32 + b];
        float hv1 = h1T_in[(q * 4 + 1) * 32 + b];
        float hv2 = h1T_in[(q * 4 + 2) * 32 + b];
        float hv3 = h1T_in[(q * 4 + 3) * 32 + b];
#pragma unroll
        for (int g = 0; g < 4; g++) {
            float4 w4 = *(const float4*)&Whh[(size_t)(g * 512 + h) * 512 + q * 4];
            acc[g] = fmaf(hv0, w4.x, fmaf(hv1, w4.y, fmaf(hv2, w4.z, fmaf(hv3, w4.w, acc[g]))));
        }
    }
    float ci = sigmf(acc[0]), cf = sigmf(acc[1]);
    float cg = tanh_(acc[2]), co = sigmf(acc[3]);
    float c = cf * c1T[h * 32 + b] + ci * cg;
    c1T[h * 32 + b] = c;
    h1T_out[h * 32 + b] = co * tanh_(c);
}

// ---------------------------------------------------------------------------
// Decoder cell 2. thread = (h in [0,128), b)
// ---------------------------------------------------------------------------
__global__ __launch_bounds__(256) void dec_cell2(
    const float* __restrict__ Wih,  // [512][512]
    const float* __restrict__ Whh,  // [512][128]
    const float* __restrict__ bias, // [512]
    const float* __restrict__ h1T,
    const float* __restrict__ h2T_in,
    float* __restrict__ h2T_out,
    float* __restrict__ c2T)
{
    int gid = blockIdx.x * 256 + threadIdx.x;
    int h = gid >> 5, b = gid & 31;

    float acc[4];
#pragma unroll
    for (int g = 0; g < 4; g++) acc[g] = bias[g * 128 + h];

#pragma unroll 2
    for (int q = 0; q < 128; q++) {
        float hv0 = h1T[(q * 4 + 0) * 32 + b];
        float hv1 = h1T[(q * 4 + 1) * 32 + b];
        float hv2 = h1T[(q * 4 + 2) * 32 + b];
        float hv3 = h1T[(q * 4 + 3) * 32 + b];
#pragma unroll
        for (int g = 0; g < 4; g++) {
            float4 w4 = *(const float4*)&Wih[(size_t)(g * 128 + h) * 512 + q * 4];
            acc[g] = fmaf(hv0, w4.x, fmaf(hv1, w4.y, fmaf(hv2, w4.z, fmaf(hv3, w4.w, acc[g]))));
        }
    }
#pragma unroll 2
    for (int q = 0; q < 32; q++) {
        float hv0 = h2T_in[(q * 4 + 0) * 32 + b];
        float hv1 = h2T_in[(q * 4 + 1) * 32 + b];
        float hv2 = h2T_in[(q * 4 + 2) * 32 + b];
        float hv3 = h2T_in[(q * 4 + 3) * 32 + b];
#pragma unroll
        for (int g = 0; g < 4; g++) {
            float4 w4 = *(const float4*)&Whh[(size_t)(g * 128 + h) * 128 + q * 4];
            acc[g] = fmaf(hv0, w4.x, fmaf(hv1, w4.y, fmaf(hv2, w4.z, fmaf(hv3, w4.w, acc[g]))));
        }
    }
    float ci = sigmf(acc[0]), cf = sigmf(acc[1]);
    float cg = tanh_(acc[2]), co = sigmf(acc[3]);
    float c = cf * c2T[h * 32 + b] + ci * cg;
    c2T[h * 32 + b] = c;
    h2T_out[h * 32 + b] = co * tanh_(c);
}

// ---------------------------------------------------------------------------
// Attention + logits. grid 32 (one WG per batch) x 256.
// ---------------------------------------------------------------------------
__global__ __launch_bounds__(256) void dec_attend(
    const float* __restrict__ key, const float* __restrict__ val, // [32][208][128]
    const float* __restrict__ h2T,   // [128][32]
    const float* __restrict__ emb,   // [30][256]
    const float* __restrict__ b_out, // [30]
    float* __restrict__ ctxT_out,    // [128][32]
    float* __restrict__ preds,       // [32][200][30]
    float* __restrict__ attn0,       // [200][208]
    int t)
{
    __shared__ __align__(16) float qv[128];
    __shared__ float av[208];
    __shared__ float red[256];
    __shared__ float ctx_s[128];
    int b = blockIdx.x, tid = threadIdx.x;

    if (tid < 128) qv[tid] = h2T[tid * 32 + b];
    __syncthreads();

    float e = -INFINITY;
    if (tid < 208) {
        float s = 0.f;
        const float* kr = key + ((size_t)b * 208 + tid) * 128;
#pragma unroll
        for (int qd = 0; qd < 32; qd++) {
            float4 k4 = *(const float4*)&kr[qd * 4];
            float4 q4 = *(const float4*)&qv[qd * 4];
            s = fmaf(k4.x, q4.x, fmaf(k4.y, q4.y, fmaf(k4.z, q4.z, fmaf(k4.w, q4.w, s))));
        }
        e = s * 0.08838834764831845f;  // 1/sqrt(128)
    }
    red[tid] = e;
    __syncthreads();
    for (int off = 128; off >= 1; off >>= 1) {
        if (tid < off) red[tid] = fmaxf(red[tid], red[tid + off]);
        __syncthreads();
    }
    float m = red[0];
    __syncthreads();
    float ex = (tid < 208) ? __expf(e - m) : 0.f;
    red[tid] = ex;
    __syncthreads();
    for (int off = 128; off >= 1; off >>= 1) {
        if (tid < off) red[tid] += red[tid + off];
        __syncthreads();
    }
    float inv = 1.0f / red[0];
    if (tid < 208) av[tid] = ex * inv;
    __syncthreads();

    if (tid < 128) {
        float s = 0.f;
        for (int ss = 0; ss < 208; ss++)
            s = fmaf(av[ss], val[((size_t)b * 208 + ss) * 128 + tid], s);
        ctx_s[tid] = s;
        ctxT_out[tid * 32 + b] = s;
    }
    __syncthreads();

    if (tid < 30) {
        float s = b_out[tid];
        const float* er = emb + tid * 256;
        for (int k = 0; k < 128; k++) s = fmaf(qv[k], er[k], s);
        for (int k = 0; k < 128; k++) s = fmaf(ctx_s[k], er[128 + k], s);
        preds[((size_t)b * 200 + t) * 30 + tid] = s;
    }
    if (b == 0 && tid < 208) attn0[t * 208 + tid] = av[tid];
}

// ---------------------------------------------------------------------------
template <typename ST>
static void run_encoder(const float* x,
                        const float* e_fw_Wih, const float* e_fw_Whh, const float* e_fw_b,
                        const float* e_bw_Wih, const float* e_bw_Whh, const float* e_bw_b,
                        const float* p_fw_Wih, const float* p_fw_Whh, const float* p_fw_b,
                        const float* p_bw_Wih, const float* p_bw_Whh, const float* p_bw_b,
                        ST* A, ST* B, float* HB, unsigned* FLG, hipStream_t stream)
{
    hipMemsetAsync(HB, 0, 32768 * 4, stream);
    hipMemsetAsync(FLG, 0, 256, stream);
    hipLaunchKernelGGL((lstm_l0<ST>), dim3(64), dim3(256), 0, stream,
                       x, e_fw_Whh, e_bw_Whh, e_fw_Wih, e_bw_Wih, e_fw_b, e_bw_b,
                       A, HB, FLG);

    int Ts[3] = {832, 416, 208};
    const ST* ins[3] = {A, B, A};
    ST* outs[3] = {B, A, B};
    for (int L = 0; L < 3; L++) {
        hipMemsetAsync(HB, 0, 32768 * 4, stream);
        hipMemsetAsync(FLG, 0, 256, stream);
        hipLaunchKernelGGL((lstm_pyr<ST>), dim3(64), dim3(256), 0, stream,
                           ins[L],
                           p_fw_Whh + (size_t)L * 1024 * 256, p_bw_Whh + (size_t)L * 1024 * 256,
                           p_fw_Wih + (size_t)L * 1024 * 1024, p_bw_Wih + (size_t)L * 1024 * 1024,
                           p_fw_b + L * 1024, p_bw_b + L * 1024,
                           outs[L], HB, FLG, Ts[L]);
    }
}

extern "C" void kernel_launch(void* const* d_in, const int* in_sizes, int n_in,
                              void* d_out, int out_size, void* d_ws, size_t ws_size,
                              hipStream_t stream)
{
    const float* x        = (const float*)d_in[0];
    // d_in[1] = x_len: constant 1664 -> enc_len = 208 = S (mask is a no-op)
    const int*   y        = (const int*)d_in[2];
    const float* e_fw_Wih = (const float*)d_in[3];
    const float* e_fw_Whh = (const float*)d_in[4];
    const float* e_fw_b   = (const float*)d_in[5];
    const float* e_bw_Wih = (const float*)d_in[6];
    const float* e_bw_Whh = (const float*)d_in[7];
    const float* e_bw_b   = (const float*)d_in[8];
    const float* p_fw_Wih = (const float*)d_in[9];
    const float* p_fw_Whh = (const float*)d_in[10];
    const float* p_fw_b   = (const float*)d_in[11];
    const float* p_bw_Wih = (const float*)d_in[12];
    const float* p_bw_Whh = (const float*)d_in[13];
    const float* p_bw_b   = (const float*)d_in[14];
    const float* Wk       = (const float*)d_in[15];
    const float* bk       = (const float*)d_in[16];
    const float* Wv       = (const float*)d_in[17];
    const float* bv       = (const float*)d_in[18];
    const float* emb      = (const float*)d_in[19];
    const float* d1_Wih   = (const float*)d_in[20];
    const float* d1_Whh   = (const float*)d_in[21];
    const float* d1_b     = (const float*)d_in[22];
    const float* d2_Wih   = (const float*)d_in[23];
    const float* d2_Whh   = (const float*)d_in[24];
    const float* d2_b     = (const float*)d_in[25];
    const float* b_out    = (const float*)d_in[26];

    char* base = (char*)d_ws;
    size_t off = 0;
    auto alloc = [&](size_t bytes) -> void* {
        void* p = base + off;
        off = (off + bytes + 255) & ~(size_t)255;
        return p;
    };

    // misc (both plans)
    float*    KEY = (float*)alloc(851968ull * 4);
    float*    VAL = (float*)alloc(851968ull * 4);
    float*    TBL = (float*)alloc(61440ull * 4);
    float*    HB  = (float*)alloc(32768ull * 4);
    unsigned* FLG = (unsigned*)alloc(1024);
    float*    H1  = (float*)alloc(32768ull * 4);
    float*    H2  = (float*)alloc(8192ull * 4);
    float*    CTX = (float*)alloc(8192ull * 4);
    float*    C1  = (float*)alloc(16384ull * 4);
    float*    C2  = (float*)alloc(4096ull * 4);

    const size_t A_elems = 32ull * 1664 * 512;  // 27,262,976
    const size_t B_elems = 32ull * 832 * 512;   // 13,631,488
    const size_t L3_elems = 32ull * 208 * 512;  //  3,407,872

    size_t misc_end = off;
    size_t need_f32  = misc_end + (A_elems + B_elems) * 4 + 2048;
    size_t need_bf16 = misc_end + L3_elems * 4 + (A_elems + B_elems) * 2 + 2048;

    const float* enc_out;  // fp32 [6656][512] view of final encoder output
    if (ws_size >= need_f32) {
        float* A = (float*)alloc(A_elems * 4);
        float* B = (float*)alloc(B_elems * 4);
        run_encoder<float>(x, e_fw_Wih, e_fw_Whh, e_fw_b, e_bw_Wih, e_bw_Whh, e_bw_b,
                           p_fw_Wih, p_fw_Whh, p_fw_b, p_bw_Wih, p_bw_Whh, p_bw_b,
                           A, B, HB, FLG, stream);
        enc_out = B;
    } else if (ws_size >= need_bf16) {
        float* CONV = (float*)alloc(L3_elems * 4);
        __hip_bfloat16* A = (__hip_bfloat16*)alloc(A_elems * 2);
        __hip_bfloat16* B = (__hip_bfloat16*)alloc(B_elems * 2);
        run_encoder<__hip_bfloat16>(x, e_fw_Wih, e_fw_Whh, e_fw_b, e_bw_Wih, e_bw_Whh, e_bw_b,
                                    p_fw_Wih, p_fw_Whh, p_fw_b, p_bw_Wih, p_bw_Whh, p_bw_b,
                                    A, B, HB, FLG, stream);
        hipLaunchKernelGGL(bf16_to_f32, dim3((unsigned)(L3_elems / 256)), dim3(256), 0, stream,
                           B, CONV, (int)L3_elems);
        enc_out = CONV;
    } else {
        return;  // workspace too small for any plan
    }

    // ---- key / val projections + decoder precompute ----
    hipLaunchKernelGGL(gemm_bt, dim3(52, 1), dim3(256), 0, stream,
                       enc_out, Wk, bk, KEY, 6656, 128, 512, 512);
    hipLaunchKernelGGL(gemm_bt, dim3(52, 1), dim3(256), 0, stream,
                       enc_out, Wv, bv, VAL, 6656, 128, 512, 512);
    hipLaunchKernelGGL(gemm_bt, dim3(1, 16), dim3(256), 0, stream,
                       emb, d1_Wih, d1_b, TBL, 30, 2048, 256, 384);
    hipLaunchKernelGGL(ctx0_kernel, dim3(16), dim3(256), 0, stream, VAL, CTX);
    hipMemsetAsync(H1, 0, 32768 * 4, stream);
    hipMemsetAsync(H2, 0, 8192 * 4, stream);
    hipMemsetAsync(C1, 0, 16384 * 4, stream);
    hipMemsetAsync(C2, 0, 4096 * 4, stream);

    float* preds = (float*)d_out;
    float* attn0 = (float*)d_out + 192000;

    for (int t = 0; t < 200; t++) {
        float* h1i = H1 + (t & 1) * 16384;
        float* h1o = H1 + ((t + 1) & 1) * 16384;
        float* h2i = H2 + (t & 1) * 4096;
        float* h2o = H2 + ((t + 1) & 1) * 4096;
        float* cxi = CTX + (t & 1) * 4096;
        float* cxo = CTX + ((t + 1) & 1) * 4096;
        hipLaunchKernelGGL(dec_cell1, dim3(64), dim3(256), 0, stream,
                           TBL, y, d1_Wih, d1_Whh, cxi, h1i, h1o, C1, t);
        hipLaunchKernelGGL(dec_cell2, dim3(16), dim3(256), 0, stream,
                           d2_Wih, d2_Whh, d2_b, h1o, h2i, h2o, C2);
        hipLaunchKernelGGL(dec_attend, dim3(32), dim3(256), 0, stream,
                           KEY, VAL, h2o, emb, b_out, cxo, preds, attn0, t);
    }
}

// Round 4
// 65886.334 us; speedup vs baseline: 1.5929x; 1.5929x over previous
//
#include <hip/hip_runtime.h>
#include <hip/hip_bf16.h>
#include <math.h>
#include <stdint.h>

// Seq2Seq LAS model. B=32, T=1664, F_IN=80, H_ENC=256, KV=128, D_DEC=512,
// EMB=256, VOCAB=30, L=200.
// R4 encoder: 256 persistent WGs (128/dir, 2 hidden units each). Per step:
// K=1280 (pyr) folded input+recurrent dot over 10x128 ping-pong LDS chunks,
// register prefetch of chunk c+1 during compute of chunk c (1 sync/chunk).
// Cross-WG step sync: monotonic flags + relaxed agent-scope atomics (same
// mechanism as R3, now 128 flags/dir) — kept identical as the controlled
// variable vs R3's neutral result.
// Decoder: 200 steps x 3 small kernels (unchanged).

#define DEV __device__ __forceinline__

DEV float sigmf(float x) { return 1.0f / (1.0f + __expf(-x)); }
DEV float tanh_(float x) { return 1.0f - 2.0f / (__expf(2.0f * x) + 1.0f); }

struct __align__(8) bf4 { __hip_bfloat16 a, b, c, d; };

DEV float4 ld4g(const float* p) { return *(const float4*)p; }
DEV float4 ld4g(const __hip_bfloat16* p) {
    bf4 v = *(const bf4*)p;
    return make_float4(__bfloat162float(v.a), __bfloat162float(v.b),
                       __bfloat162float(v.c), __bfloat162float(v.d));
}
DEV void st1g(float* p, float v) { *p = v; }
DEV void st1g(__hip_bfloat16* p, float v) { *p = __float2bfloat16(v); }

DEV float ld_coh(float* p) {
    return __hip_atomic_load(p, __ATOMIC_RELAXED, __HIP_MEMORY_SCOPE_AGENT);
}
DEV void st_coh(float* p, float v) {
    __hip_atomic_store(p, v, __ATOMIC_RELAXED, __HIP_MEMORY_SCOPE_AGENT);
}

// ---------------------------------------------------------------------------
// step barrier among 128 WGs of one direction (monotonic flag counters).
// __syncthreads drains vmcnt (coherent h-stores visible) before flag store.
// ---------------------------------------------------------------------------
DEV void step_barrier(unsigned* myflags, int w, int tid, unsigned tv)
{
    __syncthreads();
    if (tid == 0)
        __hip_atomic_store(&myflags[w], tv, __ATOMIC_RELAXED,
                           __HIP_MEMORY_SCOPE_AGENT);
    if (tid < 128) {
        int guard = 0;
        while (__hip_atomic_load(&myflags[tid], __ATOMIC_RELAXED,
                                 __HIP_MEMORY_SCOPE_AGENT) < tv) {
            __builtin_amdgcn_s_sleep(1);
            if (++guard > (1 << 15)) break;  // anti-hang: fail loud, not forever
        }
    }
    __syncthreads();
}

// ---------------------------------------------------------------------------
// Encoder layer 0 (persistent). K = 384 = 2x128 h-chunks + 1 chunk (80 x + 48
// pad). grid 256: dir = blk>>7, w = blk&127 (owns hidden units w*2, w*2+1).
// hbuf: [dir][parity][b][256]; flags: [dir][128].
// Lane roles: cl = lane&7 -> gate-col (gate=cl>>1, unit j=cl&1);
//             slot = (wave*8 + (lane>>3))*4 -> 4-float k-slice per chunk.
// ---------------------------------------------------------------------------
template <typename ST>
__global__ __launch_bounds__(256, 1) void lstm_l0(
    const float* __restrict__ x,        // [32][1664][80]
    const float* __restrict__ whh_f, const float* __restrict__ whh_b,  // [1024][256]
    const float* __restrict__ wih_f, const float* __restrict__ wih_b,  // [1024][80]
    const float* __restrict__ bias_f, const float* __restrict__ bias_b,
    ST* __restrict__ out,               // [32][1664][512]
    float* __restrict__ hbuf, unsigned* __restrict__ flags)
{
    const int T = 1664;
    __shared__ __align__(16) float hs[2][32][128];
    __shared__ float pb[4][32][9];
    __shared__ float gs[32][8];

    const int tid = threadIdx.x;
    const int dir = blockIdx.x >> 7;
    const int w = blockIdx.x & 127;
    const int wave = tid >> 6, lane = tid & 63;
    const int cl = lane & 7;
    const int ksub = lane >> 3;
    const int slot = (wave * 8 + ksub) * 4;
    const int col = (cl >> 1) * 256 + w * 2 + (cl & 1);

    const float* Whh = dir ? whh_b : whh_f;
    const float* Wih = dir ? wih_b : wih_f;
    const float* bias = dir ? bias_b : bias_f;

    float4 wreg[3];
#pragma unroll
    for (int c = 0; c < 3; c++) {
        int k = c * 128 + slot;
        float4 v = make_float4(0.f, 0.f, 0.f, 0.f);
        if (k < 256) v = *(const float4*)&Whh[(size_t)col * 256 + k];
        else if (k - 256 < 80) v = *(const float4*)&Wih[(size_t)col * 80 + (k - 256)];
        wreg[c] = v;
    }
    const float bias_cl = bias[col];

    const int sb = tid >> 3, sk = (tid & 7) * 16;  // staging role
    const int qb = tid >> 1, qj = tid & 1;         // update role (tid<64)
    float c_reg = 0.f;

    unsigned* myflags = flags + dir * 128;
    float* hb_base = hbuf + dir * 2 * 8192;

    for (int t = 0; t < T; t++) {
        const int par = t & 1;
        const int t_act = dir ? (T - 1 - t) : t;
        float* hin = hb_base + par * 8192;

        // stage chunk 0 (h[:,0:128], coherent)
#pragma unroll
        for (int i = 0; i < 16; i++)
            hs[0][sb][sk + i] = ld_coh(&hin[sb * 256 + sk + i]);
        __syncthreads();

        float acc[32];
#pragma unroll
        for (int b = 0; b < 32; b++) acc[b] = 0.f;

        float pfh[16];
        float4 pf[4];

#pragma unroll
        for (int c = 0; c < 3; c++) {
            // prefetch chunk c+1
            if (c == 0) {
#pragma unroll
                for (int i = 0; i < 16; i++)
                    pfh[i] = ld_coh(&hin[sb * 256 + 128 + sk + i]);
            } else if (c == 1) {
                if (sk < 80) {
                    const float* src = &x[((size_t)sb * 1664 + t_act) * 80 + sk];
#pragma unroll
                    for (int i = 0; i < 4; i++) pf[i] = *(const float4*)(src + i * 4);
                } else {
#pragma unroll
                    for (int i = 0; i < 4; i++) pf[i] = make_float4(0.f, 0.f, 0.f, 0.f);
                }
            }
            // compute chunk c
            const float* hc = &hs[c & 1][0][0];
            float4 wv = wreg[c];
#pragma unroll
            for (int b = 0; b < 32; b++) {
                float4 hv = *(const float4*)&hc[b * 128 + slot];
                acc[b] = fmaf(hv.x, wv.x, fmaf(hv.y, wv.y, fmaf(hv.z, wv.z, fmaf(hv.w, wv.w, acc[b]))));
            }
            // commit prefetch into the other buffer
            if (c == 0) {
#pragma unroll
                for (int i = 0; i < 16; i++) hs[1][sb][sk + i] = pfh[i];
                __syncthreads();
            } else if (c == 1) {
#pragma unroll
                for (int i = 0; i < 4; i++) *(float4*)&hs[0][sb][sk + i * 4] = pf[i];
                __syncthreads();
            }
        }

        // reduce 8 k-slices within wave (lane bits 3..5)
#pragma unroll
        for (int b = 0; b < 32; b++) {
            acc[b] += __shfl_xor(acc[b], 8, 64);
            acc[b] += __shfl_xor(acc[b], 16, 64);
            acc[b] += __shfl_xor(acc[b], 32, 64);
        }
#pragma unroll
        for (int i = 0; i < 4; i++)
            pb[wave][ksub * 4 + i][cl] = acc[ksub * 4 + i];
        __syncthreads();

        // sum 4 waves + bias -> gate value for (b=sb, cl)
        {
            float g = bias_cl;
#pragma unroll
            for (int v = 0; v < 4; v++) g += pb[v][sb][tid & 7];
            gs[sb][tid & 7] = g;
        }
        __syncthreads();

        if (tid < 64) {
            float gi = gs[qb][0 + qj], gf = gs[qb][2 + qj];
            float gg = gs[qb][4 + qj], go = gs[qb][6 + qj];
            float ci = sigmf(gi), cf = sigmf(gf), cg = tanh_(gg), co = sigmf(go);
            c_reg = cf * c_reg + ci * cg;
            float hval = co * tanh_(c_reg);
            st_coh(&hb_base[(par ^ 1) * 8192 + qb * 256 + w * 2 + qj], hval);
            st1g(&out[((size_t)qb * T + t_act) * 512 + dir * 256 + w * 2 + qj], hval);
        }

        step_barrier(myflags, w, tid, (unsigned)(t + 1));
    }
}

// ---------------------------------------------------------------------------
// Pyramid layer (persistent). K = 1280 = 2 h-chunks + 8 input chunks of 128.
// Input chunk c (c>=2): row 2t + ((c-2)>>2), cols ((c-2)*128)&511 .. +128.
// ---------------------------------------------------------------------------
template <typename ST>
__global__ __launch_bounds__(256, 1) void lstm_pyr(
    const ST* __restrict__ in,          // [32][2*Tn][512]
    const float* __restrict__ whh_f, const float* __restrict__ whh_b,  // [1024][256]
    const float* __restrict__ wih_f, const float* __restrict__ wih_b,  // [1024][1024]
    const float* __restrict__ bias_f, const float* __restrict__ bias_b,
    ST* __restrict__ out,               // [32][Tn][512]
    float* __restrict__ hbuf, unsigned* __restrict__ flags, int Tn)
{
    __shared__ __align__(16) float hs[2][32][128];
    __shared__ float pb[4][32][9];
    __shared__ float gs[32][8];

    const int tid = threadIdx.x;
    const int dir = blockIdx.x >> 7;
    const int w = blockIdx.x & 127;
    const int wave = tid >> 6, lane = tid & 63;
    const int cl = lane & 7;
    const int ksub = lane >> 3;
    const int slot = (wave * 8 + ksub) * 4;
    const int col = (cl >> 1) * 256 + w * 2 + (cl & 1);
    const int Tprev = 2 * Tn;

    const float* Whh = dir ? whh_b : whh_f;
    const float* Wih = dir ? wih_b : wih_f;
    const float* bias = dir ? bias_b : bias_f;

    float4 wreg[10];
#pragma unroll
    for (int c = 0; c < 10; c++) {
        int k = c * 128 + slot;
        wreg[c] = (k < 256)
            ? *(const float4*)&Whh[(size_t)col * 256 + k]
            : *(const float4*)&Wih[(size_t)col * 1024 + (k - 256)];
    }
    const float bias_cl = bias[col];

    const int sb = tid >> 3, sk = (tid & 7) * 16;
    const int qb = tid >> 1, qj = tid & 1;
    float c_reg = 0.f;

    unsigned* myflags = flags + dir * 128;
    float* hb_base = hbuf + dir * 2 * 8192;

    for (int t = 0; t < Tn; t++) {
        const int par = t & 1;
        const int t_act = dir ? (Tn - 1 - t) : t;
        float* hin = hb_base + par * 8192;

        // stage chunk 0 (h[:,0:128], coherent)
#pragma unroll
        for (int i = 0; i < 16; i++)
            hs[0][sb][sk + i] = ld_coh(&hin[sb * 256 + sk + i]);
        __syncthreads();

        float acc[32];
#pragma unroll
        for (int b = 0; b < 32; b++) acc[b] = 0.f;

        float pfh[16];
        float4 pf[4];

#pragma unroll
        for (int c = 0; c < 10; c++) {
            // prefetch chunk c+1
            if (c == 0) {
#pragma unroll
                for (int i = 0; i < 16; i++)
                    pfh[i] = ld_coh(&hin[sb * 256 + 128 + sk + i]);
            } else if (c < 9) {
                int base = (c - 1) * 128;          // input-k base of chunk c+1
                int r = 2 * t_act + (base >> 9);
                const ST* src = &in[((size_t)sb * Tprev + r) * 512 + (base & 511) + sk];
#pragma unroll
                for (int i = 0; i < 4; i++) pf[i] = ld4g(src + i * 4);
            }
            // compute chunk c
            const float* hc = &hs[c & 1][0][0];
            float4 wv = wreg[c];
#pragma unroll
            for (int b = 0; b < 32; b++) {
                float4 hv = *(const float4*)&hc[b * 128 + slot];
                acc[b] = fmaf(hv.x, wv.x, fmaf(hv.y, wv.y, fmaf(hv.z, wv.z, fmaf(hv.w, wv.w, acc[b]))));
            }
            // commit prefetch into the other buffer
            if (c == 0) {
#pragma unroll
                for (int i = 0; i < 16; i++) hs[1][sb][sk + i] = pfh[i];
                __syncthreads();
            } else if (c < 9) {
#pragma unroll
                for (int i = 0; i < 4; i++) *(float4*)&hs[(c + 1) & 1][sb][sk + i * 4] = pf[i];
                __syncthreads();
            }
        }

#pragma unroll
        for (int b = 0; b < 32; b++) {
            acc[b] += __shfl_xor(acc[b], 8, 64);
            acc[b] += __shfl_xor(acc[b], 16, 64);
            acc[b] += __shfl_xor(acc[b], 32, 64);
        }
#pragma unroll
        for (int i = 0; i < 4; i++)
            pb[wave][ksub * 4 + i][cl] = acc[ksub * 4 + i];
        __syncthreads();

        {
            float g = bias_cl;
#pragma unroll
            for (int v = 0; v < 4; v++) g += pb[v][sb][tid & 7];
            gs[sb][tid & 7] = g;
        }
        __syncthreads();

        if (tid < 64) {
            float gi = gs[qb][0 + qj], gf = gs[qb][2 + qj];
            float gg = gs[qb][4 + qj], go = gs[qb][6 + qj];
            float ci = sigmf(gi), cf = sigmf(gf), cg = tanh_(gg), co = sigmf(go);
            c_reg = cf * c_reg + ci * cg;
            float hval = co * tanh_(c_reg);
            st_coh(&hb_base[(par ^ 1) * 8192 + qb * 256 + w * 2 + qj], hval);
            st1g(&out[((size_t)qb * Tn + t_act) * 512 + dir * 256 + w * 2 + qj], hval);
        }

        step_barrier(myflags, w, tid, (unsigned)(t + 1));
    }
}

// ---------------------------------------------------------------------------
// C[M][N] = A[M][K] @ W[N][K]^T + bias  (fp32, 128x128 tiles, 8x8/thread)
// ---------------------------------------------------------------------------
__global__ __launch_bounds__(256) void gemm_bt(
    const float* __restrict__ A, const float* __restrict__ W,
    const float* __restrict__ bias, float* __restrict__ C,
    int M, int N, int K, int ldw)
{
    __shared__ __align__(16) float As[16][128];
    __shared__ __align__(16) float Ws[16][128];
    int tid = threadIdx.x;
    int m0 = blockIdx.x * 128, n0 = blockIdx.y * 128;
    int tx = tid & 15, ty = tid >> 4;

    float acc[8][8];
#pragma unroll
    for (int i = 0; i < 8; i++)
#pragma unroll
        for (int j = 0; j < 8; j++) acc[i][j] = 0.f;

    for (int kb = 0; kb < K; kb += 16) {
#pragma unroll
        for (int l = 0; l < 2; l++) {
            int idx = tid + l * 256;
            int row = idx >> 2, kq = (idx & 3) * 4;
            float4 v = make_float4(0.f, 0.f, 0.f, 0.f);
            if (m0 + row < M)
                v = *(const float4*)&A[(size_t)(m0 + row) * K + kb + kq];
            As[kq + 0][row] = v.x; As[kq + 1][row] = v.y;
            As[kq + 2][row] = v.z; As[kq + 3][row] = v.w;
        }
#pragma unroll
        for (int l = 0; l < 2; l++) {
            int idx = tid + l * 256;
            int row = idx >> 2, kq = (idx & 3) * 4;
            float4 v = *(const float4*)&W[(size_t)(n0 + row) * ldw + kb + kq];
            Ws[kq + 0][row] = v.x; Ws[kq + 1][row] = v.y;
            Ws[kq + 2][row] = v.z; Ws[kq + 3][row] = v.w;
        }
        __syncthreads();
#pragma unroll
        for (int k = 0; k < 16; k++) {
            float a[8], b[8];
            *(float4*)&a[0] = *(const float4*)&As[k][ty * 8];
            *(float4*)&a[4] = *(const float4*)&As[k][ty * 8 + 4];
            *(float4*)&b[0] = *(const float4*)&Ws[k][tx * 8];
            *(float4*)&b[4] = *(const float4*)&Ws[k][tx * 8 + 4];
#pragma unroll
            for (int i = 0; i < 8; i++)
#pragma unroll
                for (int j = 0; j < 8; j++)
                    acc[i][j] = fmaf(a[i], b[j], acc[i][j]);
        }
        __syncthreads();
    }
#pragma unroll
    for (int i = 0; i < 8; i++) {
        int m = m0 + ty * 8 + i;
        if (m >= M) continue;
#pragma unroll
        for (int j = 0; j < 8; j++)
            C[(size_t)m * N + n0 + tx * 8 + j] = acc[i][j] + bias[n0 + tx * 8 + j];
    }
}

__global__ void bf16_to_f32(const __hip_bfloat16* __restrict__ in,
                            float* __restrict__ out, int n)
{
    int i = blockIdx.x * 256 + threadIdx.x;
    if (i < n) out[i] = __bfloat162float(in[i]);
}

// ---------------------------------------------------------------------------
// ctx0 = mean over s of val[b][s][k] -> ctxT [128][32]
// ---------------------------------------------------------------------------
__global__ void ctx0_kernel(const float* __restrict__ val, float* __restrict__ ctxT)
{
    int gid = blockIdx.x * 256 + threadIdx.x;
    if (gid >= 4096) return;
    int k = gid >> 5, b = gid & 31;
    float s = 0.f;
    for (int t = 0; t < 208; t++) s += val[((size_t)b * 208 + t) * 128 + k];
    ctxT[k * 32 + b] = s * (1.0f / 208.0f);
}

// ---------------------------------------------------------------------------
// Decoder cell 1. thread = (h = gid>>5 in [0,512), b = gid&31)
// ---------------------------------------------------------------------------
__global__ __launch_bounds__(256) void dec_cell1(
    const float* __restrict__ table,   // [30][2048] = emb@Wih[:, :256]^T + d1_b
    const int* __restrict__ y,         // [32][200]
    const float* __restrict__ Wih,     // [2048][384]
    const float* __restrict__ Whh,     // [2048][512]
    const float* __restrict__ ctxT_in, // [128][32]
    const float* __restrict__ h1T_in,  // [512][32]
    float* __restrict__ h1T_out,
    float* __restrict__ c1T,
    int t)
{
    int gid = blockIdx.x * 256 + threadIdx.x;
    int h = gid >> 5, b = gid & 31;
    int tok = (t == 0) ? 0 : y[b * 200 + t - 1];

    float acc[4];
#pragma unroll
    for (int g = 0; g < 4; g++) acc[g] = table[tok * 2048 + g * 512 + h];

#pragma unroll 2
    for (int q = 0; q < 32; q++) {
        float hv0 = ctxT_in[(q * 4 + 0) * 32 + b];
        float hv1 = ctxT_in[(q * 4 + 1) * 32 + b];
        float hv2 = ctxT_in[(q * 4 + 2) * 32 + b];
        float hv3 = ctxT_in[(q * 4 + 3) * 32 + b];
#pragma unroll
        for (int g = 0; g < 4; g++) {
            float4 w4 = *(const float4*)&Wih[(size_t)(g * 512 + h) * 384 + 256 + q * 4];
            acc[g] = fmaf(hv0, w4.x, fmaf(hv1, w4.y, fmaf(hv2, w4.z, fmaf(hv3, w4.w, acc[g]))));
        }
    }
#pragma unroll 2
    for (int q = 0; q < 128; q++) {
        float hv0 = h1T_in[(q * 4 + 0) * 32 + b];
        float hv1 = h1T_in[(q * 4 + 1) * 32 + b];
        float hv2 = h1T_in[(q * 4 + 2) * 32 + b];
        float hv3 = h1T_in[(q * 4 + 3) * 32 + b];
#pragma unroll
        for (int g = 0; g < 4; g++) {
            float4 w4 = *(const float4*)&Whh[(size_t)(g * 512 + h) * 512 + q * 4];
            acc[g] = fmaf(hv0, w4.x, fmaf(hv1, w4.y, fmaf(hv2, w4.z, fmaf(hv3, w4.w, acc[g]))));
        }
    }
    float ci = sigmf(acc[0]), cf = sigmf(acc[1]);
    float cg = tanh_(acc[2]), co = sigmf(acc[3]);
    float c = cf * c1T[h * 32 + b] + ci * cg;
    c1T[h * 32 + b] = c;
    h1T_out[h * 32 + b] = co * tanh_(c);
}

// ---------------------------------------------------------------------------
// Decoder cell 2. thread = (h in [0,128), b)
// ---------------------------------------------------------------------------
__global__ __launch_bounds__(256) void dec_cell2(
    const float* __restrict__ Wih,  // [512][512]
    const float* __restrict__ Whh,  // [512][128]
    const float* __restrict__ bias, // [512]
    const float* __restrict__ h1T,
    const float* __restrict__ h2T_in,
    float* __restrict__ h2T_out,
    float* __restrict__ c2T)
{
    int gid = blockIdx.x * 256 + threadIdx.x;
    int h = gid >> 5, b = gid & 31;

    float acc[4];
#pragma unroll
    for (int g = 0; g < 4; g++) acc[g] = bias[g * 128 + h];

#pragma unroll 2
    for (int q = 0; q < 128; q++) {
        float hv0 = h1T[(q * 4 + 0) * 32 + b];
        float hv1 = h1T[(q * 4 + 1) * 32 + b];
        float hv2 = h1T[(q * 4 + 2) * 32 + b];
        float hv3 = h1T[(q * 4 + 3) * 32 + b];
#pragma unroll
        for (int g = 0; g < 4; g++) {
            float4 w4 = *(const float4*)&Wih[(size_t)(g * 128 + h) * 512 + q * 4];
            acc[g] = fmaf(hv0, w4.x, fmaf(hv1, w4.y, fmaf(hv2, w4.z, fmaf(hv3, w4.w, acc[g]))));
        }
    }
#pragma unroll 2
    for (int q = 0; q < 32; q++) {
        float hv0 = h2T_in[(q * 4 + 0) * 32 + b];
        float hv1 = h2T_in[(q * 4 + 1) * 32 + b];
        float hv2 = h2T_in[(q * 4 + 2) * 32 + b];
        float hv3 = h2T_in[(q * 4 + 3) * 32 + b];
#pragma unroll
        for (int g = 0; g < 4; g++) {
            float4 w4 = *(const float4*)&Whh[(size_t)(g * 128 + h) * 128 + q * 4];
            acc[g] = fmaf(hv0, w4.x, fmaf(hv1, w4.y, fmaf(hv2, w4.z, fmaf(hv3, w4.w, acc[g]))));
        }
    }
    float ci = sigmf(acc[0]), cf = sigmf(acc[1]);
    float cg = tanh_(acc[2]), co = sigmf(acc[3]);
    float c = cf * c2T[h * 32 + b] + ci * cg;
    c2T[h * 32 + b] = c;
    h2T_out[h * 32 + b] = co * tanh_(c);
}

// ---------------------------------------------------------------------------
// Attention + logits. grid 32 (one WG per batch) x 256.
// ---------------------------------------------------------------------------
__global__ __launch_bounds__(256) void dec_attend(
    const float* __restrict__ key, const float* __restrict__ val, // [32][208][128]
    const float* __restrict__ h2T,   // [128][32]
    const float* __restrict__ emb,   // [30][256]
    const float* __restrict__ b_out, // [30]
    float* __restrict__ ctxT_out,    // [128][32]
    float* __restrict__ preds,       // [32][200][30]
    float* __restrict__ attn0,       // [200][208]
    int t)
{
    __shared__ __align__(16) float qv[128];
    __shared__ float av[208];
    __shared__ float red[256];
    __shared__ float ctx_s[128];
    int b = blockIdx.x, tid = threadIdx.x;

    if (tid < 128) qv[tid] = h2T[tid * 32 + b];
    __syncthreads();

    float e = -INFINITY;
    if (tid < 208) {
        float s = 0.f;
        const float* kr = key + ((size_t)b * 208 + tid) * 128;
#pragma unroll
        for (int qd = 0; qd < 32; qd++) {
            float4 k4 = *(const float4*)&kr[qd * 4];
            float4 q4 = *(const float4*)&qv[qd * 4];
            s = fmaf(k4.x, q4.x, fmaf(k4.y, q4.y, fmaf(k4.z, q4.z, fmaf(k4.w, q4.w, s))));
        }
        e = s * 0.08838834764831845f;  // 1/sqrt(128)
    }
    red[tid] = e;
    __syncthreads();
    for (int off = 128; off >= 1; off >>= 1) {
        if (tid < off) red[tid] = fmaxf(red[tid], red[tid + off]);
        __syncthreads();
    }
    float m = red[0];
    __syncthreads();
    float ex = (tid < 208) ? __expf(e - m) : 0.f;
    red[tid] = ex;
    __syncthreads();
    for (int off = 128; off >= 1; off >>= 1) {
        if (tid < off) red[tid] += red[tid + off];
        __syncthreads();
    }
    float inv = 1.0f / red[0];
    if (tid < 208) av[tid] = ex * inv;
    __syncthreads();

    if (tid < 128) {
        float s = 0.f;
        for (int ss = 0; ss < 208; ss++)
            s = fmaf(av[ss], val[((size_t)b * 208 + ss) * 128 + tid], s);
        ctx_s[tid] = s;
        ctxT_out[tid * 32 + b] = s;
    }
    __syncthreads();

    if (tid < 30) {
        float s = b_out[tid];
        const float* er = emb + tid * 256;
        for (int k = 0; k < 128; k++) s = fmaf(qv[k], er[k], s);
        for (int k = 0; k < 128; k++) s = fmaf(ctx_s[k], er[128 + k], s);
        preds[((size_t)b * 200 + t) * 30 + tid] = s;
    }
    if (b == 0 && tid < 208) attn0[t * 208 + tid] = av[tid];
}

// ---------------------------------------------------------------------------
template <typename ST>
static void run_encoder(const float* x,
                        const float* e_fw_Wih, const float* e_fw_Whh, const float* e_fw_b,
                        const float* e_bw_Wih, const float* e_bw_Whh, const float* e_bw_b,
                        const float* p_fw_Wih, const float* p_fw_Whh, const float* p_fw_b,
                        const float* p_bw_Wih, const float* p_bw_Whh, const float* p_bw_b,
                        ST* A, ST* B, float* HB, unsigned* FLG, hipStream_t stream)
{
    hipMemsetAsync(HB, 0, 32768 * 4, stream);
    hipMemsetAsync(FLG, 0, 1024, stream);
    hipLaunchKernelGGL((lstm_l0<ST>), dim3(256), dim3(256), 0, stream,
                       x, e_fw_Whh, e_bw_Whh, e_fw_Wih, e_bw_Wih, e_fw_b, e_bw_b,
                       A, HB, FLG);

    int Ts[3] = {832, 416, 208};
    const ST* ins[3] = {A, B, A};
    ST* outs[3] = {B, A, B};
    for (int L = 0; L < 3; L++) {
        hipMemsetAsync(HB, 0, 32768 * 4, stream);
        hipMemsetAsync(FLG, 0, 1024, stream);
        hipLaunchKernelGGL((lstm_pyr<ST>), dim3(256), dim3(256), 0, stream,
                           ins[L],
                           p_fw_Whh + (size_t)L * 1024 * 256, p_bw_Whh + (size_t)L * 1024 * 256,
                           p_fw_Wih + (size_t)L * 1024 * 1024, p_bw_Wih + (size_t)L * 1024 * 1024,
                           p_fw_b + L * 1024, p_bw_b + L * 1024,
                           outs[L], HB, FLG, Ts[L]);
    }
}

extern "C" void kernel_launch(void* const* d_in, const int* in_sizes, int n_in,
                              void* d_out, int out_size, void* d_ws, size_t ws_size,
                              hipStream_t stream)
{
    const float* x        = (const float*)d_in[0];
    // d_in[1] = x_len: constant 1664 -> enc_len = 208 = S (mask is a no-op)
    const int*   y        = (const int*)d_in[2];
    const float* e_fw_Wih = (const float*)d_in[3];
    const float* e_fw_Whh = (const float*)d_in[4];
    const float* e_fw_b   = (const float*)d_in[5];
    const float* e_bw_Wih = (const float*)d_in[6];
    const float* e_bw_Whh = (const float*)d_in[7];
    const float* e_bw_b   = (const float*)d_in[8];
    const float* p_fw_Wih = (const float*)d_in[9];
    const float* p_fw_Whh = (const float*)d_in[10];
    const float* p_fw_b   = (const float*)d_in[11];
    const float* p_bw_Wih = (const float*)d_in[12];
    const float* p_bw_Whh = (const float*)d_in[13];
    const float* p_bw_b   = (const float*)d_in[14];
    const float* Wk       = (const float*)d_in[15];
    const float* bk       = (const float*)d_in[16];
    const float* Wv       = (const float*)d_in[17];
    const float* bv       = (const float*)d_in[18];
    const float* emb      = (const float*)d_in[19];
    const float* d1_Wih   = (const float*)d_in[20];
    const float* d1_Whh   = (const float*)d_in[21];
    const float* d1_b     = (const float*)d_in[22];
    const float* d2_Wih   = (const float*)d_in[23];
    const float* d2_Whh   = (const float*)d_in[24];
    const float* d2_b     = (const float*)d_in[25];
    const float* b_out    = (const float*)d_in[26];

    char* base = (char*)d_ws;
    size_t off = 0;
    auto alloc = [&](size_t bytes) -> void* {
        void* p = base + off;
        off = (off + bytes + 255) & ~(size_t)255;
        return p;
    };

    // misc (both plans)
    float*    KEY = (float*)alloc(851968ull * 4);
    float*    VAL = (float*)alloc(851968ull * 4);
    float*    TBL = (float*)alloc(61440ull * 4);
    float*    HB  = (float*)alloc(32768ull * 4);
    unsigned* FLG = (unsigned*)alloc(1024);
    float*    H1  = (float*)alloc(32768ull * 4);
    float*    H2  = (float*)alloc(8192ull * 4);
    float*    CTX = (float*)alloc(8192ull * 4);
    float*    C1  = (float*)alloc(16384ull * 4);
    float*    C2  = (float*)alloc(4096ull * 4);

    const size_t A_elems = 32ull * 1664 * 512;  // 27,262,976
    const size_t B_elems = 32ull * 832 * 512;   // 13,631,488
    const size_t L3_elems = 32ull * 208 * 512;  //  3,407,872

    size_t misc_end = off;
    size_t need_f32  = misc_end + (A_elems + B_elems) * 4 + 2048;
    size_t need_bf16 = misc_end + L3_elems * 4 + (A_elems + B_elems) * 2 + 2048;

    const float* enc_out;  // fp32 [6656][512] view of final encoder output
    if (ws_size >= need_f32) {
        float* A = (float*)alloc(A_elems * 4);
        float* B = (float*)alloc(B_elems * 4);
        run_encoder<float>(x, e_fw_Wih, e_fw_Whh, e_fw_b, e_bw_Wih, e_bw_Whh, e_bw_b,
                           p_fw_Wih, p_fw_Whh, p_fw_b, p_bw_Wih, p_bw_Whh, p_bw_b,
                           A, B, HB, FLG, stream);
        enc_out = B;
    } else if (ws_size >= need_bf16) {
        float* CONV = (float*)alloc(L3_elems * 4);
        __hip_bfloat16* A = (__hip_bfloat16*)alloc(A_elems * 2);
        __hip_bfloat16* B = (__hip_bfloat16*)alloc(B_elems * 2);
        run_encoder<__hip_bfloat16>(x, e_fw_Wih, e_fw_Whh, e_fw_b, e_bw_Wih, e_bw_Whh, e_bw_b,
                                    p_fw_Wih, p_fw_Whh, p_fw_b, p_bw_Wih, p_bw_Whh, p_bw_b,
                                    A, B, HB, FLG, stream);
        hipLaunchKernelGGL(bf16_to_f32, dim3((unsigned)(L3_elems / 256)), dim3(256), 0, stream,
                           B, CONV, (int)L3_elems);
        enc_out = CONV;
    } else {
        return;  // workspace too small for any plan
    }

    // ---- key / val projections + decoder precompute ----
    hipLaunchKernelGGL(gemm_bt, dim3(52, 1), dim3(256), 0, stream,
                       enc_out, Wk, bk, KEY, 6656, 128, 512, 512);
    hipLaunchKernelGGL(gemm_bt, dim3(52, 1), dim3(256), 0, stream,
                       enc_out, Wv, bv, VAL, 6656, 128, 512, 512);
    hipLaunchKernelGGL(gemm_bt, dim3(1, 16), dim3(256), 0, stream,
                       emb, d1_Wih, d1_b, TBL, 30, 2048, 256, 384);
    hipLaunchKernelGGL(ctx0_kernel, dim3(16), dim3(256), 0, stream, VAL, CTX);
    hipMemsetAsync(H1, 0, 32768 * 4, stream);
    hipMemsetAsync(H2, 0, 8192 * 4, stream);
    hipMemsetAsync(C1, 0, 16384 * 4, stream);
    hipMemsetAsync(C2, 0, 4096 * 4, stream);

    float* preds = (float*)d_out;
    float* attn0 = (float*)d_out + 192000;

    for (int t = 0; t < 200; t++) {
        float* h1i = H1 + (t & 1) * 16384;
        float* h1o = H1 + ((t + 1) & 1) * 16384;
        float* h2i = H2 + (t & 1) * 4096;
        float* h2o = H2 + ((t + 1) & 1) * 4096;
        float* cxi = CTX + (t & 1) * 4096;
        float* cxo = CTX + ((t + 1) & 1) * 4096;
        hipLaunchKernelGGL(dec_cell1, dim3(64), dim3(256), 0, stream,
                           TBL, y, d1_Wih, d1_Whh, cxi, h1i, h1o, C1, t);
        hipLaunchKernelGGL(dec_cell2, dim3(16), dim3(256), 0, stream,
                           d2_Wih, d2_Whh, d2_b, h1o, h2i, h2o, C2);
        hipLaunchKernelGGL(dec_attend, dim3(32), dim3(256), 0, stream,
                           KEY, VAL, h2o, emb, b_out, cxo, preds, attn0, t);
    }
}

// Round 5
// 53698.743 us; speedup vs baseline: 1.9544x; 1.2270x over previous
//
#include <hip/hip_runtime.h>
#include <hip/hip_bf16.h>
#include <math.h>
#include <stdint.h>

// Seq2Seq LAS model. B=32, T=1664, F_IN=80, H_ENC=256, KV=128, D_DEC=512,
// EMB=256, VOCAB=30, L=200.
// R5 encoder: 256 persistent WGs (128/dir, 2 hidden units each), with
//  (a) +64KB dynamic LDS per WG -> forces 1 WG/CU (kills co-residency skew:
//      the per-step barrier gates everyone on the slowest WG, so one CU
//      hosting 2 WGs doubles EVERY step),
//  (b) flags strided 1-per-64B-line (no IC same-line store serialization),
//  (c) both h chunks' coherent loads issued back-to-back (one fewer exposed
//      IC round trip per step).
// Sync mechanism itself (monotonic flags, relaxed agent atomics) unchanged.
// Decoder: 200 steps x 3 small kernels (unchanged; next optimization target).

#define DEV __device__ __forceinline__

#define FLAG_STRIDE 16  // dwords; one flag per 64B line

DEV float sigmf(float x) { return 1.0f / (1.0f + __expf(-x)); }
DEV float tanh_(float x) { return 1.0f - 2.0f / (__expf(2.0f * x) + 1.0f); }

struct __align__(8) bf4 { __hip_bfloat16 a, b, c, d; };

DEV float4 ld4g(const float* p) { return *(const float4*)p; }
DEV float4 ld4g(const __hip_bfloat16* p) {
    bf4 v = *(const bf4*)p;
    return make_float4(__bfloat162float(v.a), __bfloat162float(v.b),
                       __bfloat162float(v.c), __bfloat162float(v.d));
}
DEV void st1g(float* p, float v) { *p = v; }
DEV void st1g(__hip_bfloat16* p, float v) { *p = __float2bfloat16(v); }

DEV float ld_coh(float* p) {
    return __hip_atomic_load(p, __ATOMIC_RELAXED, __HIP_MEMORY_SCOPE_AGENT);
}
DEV void st_coh(float* p, float v) {
    __hip_atomic_store(p, v, __ATOMIC_RELAXED, __HIP_MEMORY_SCOPE_AGENT);
}

extern __shared__ float dyn_pad[];  // unused; launch-time 64KB to pin 1 WG/CU

// ---------------------------------------------------------------------------
// step barrier among 128 WGs of one direction. Flags strided 64B apart.
// __syncthreads drains vmcnt (coherent h-stores visible) before flag store.
// ---------------------------------------------------------------------------
DEV void step_barrier(unsigned* myflags, int w, int tid, unsigned tv)
{
    __syncthreads();
    if (tid == 0)
        __hip_atomic_store(&myflags[w * FLAG_STRIDE], tv, __ATOMIC_RELAXED,
                           __HIP_MEMORY_SCOPE_AGENT);
    if (tid < 128) {
        int guard = 0;
        while (__hip_atomic_load(&myflags[tid * FLAG_STRIDE], __ATOMIC_RELAXED,
                                 __HIP_MEMORY_SCOPE_AGENT) < tv) {
            __builtin_amdgcn_s_sleep(1);
            if (++guard > (1 << 15)) break;  // anti-hang: fail loud, not forever
        }
    }
    __syncthreads();
}

// ---------------------------------------------------------------------------
// Encoder layer 0 (persistent). K = 384 = 2x128 h-chunks + 1 chunk (80 x + 48
// pad). grid 256: dir = blk>>7, w = blk&127 (owns hidden units w*2, w*2+1).
// hbuf: [dir][parity][b][256]; flags: [dir][128*FLAG_STRIDE].
// ---------------------------------------------------------------------------
template <typename ST>
__global__ __launch_bounds__(256, 1) void lstm_l0(
    const float* __restrict__ x,        // [32][1664][80]
    const float* __restrict__ whh_f, const float* __restrict__ whh_b,  // [1024][256]
    const float* __restrict__ wih_f, const float* __restrict__ wih_b,  // [1024][80]
    const float* __restrict__ bias_f, const float* __restrict__ bias_b,
    ST* __restrict__ out,               // [32][1664][512]
    float* __restrict__ hbuf, unsigned* __restrict__ flags)
{
    const int T = 1664;
    __shared__ __align__(16) float hs[2][32][128];
    __shared__ float pb[4][32][9];
    __shared__ float gs[32][8];

    const int tid = threadIdx.x;
    const int dir = blockIdx.x >> 7;
    const int w = blockIdx.x & 127;
    const int wave = tid >> 6, lane = tid & 63;
    const int cl = lane & 7;
    const int ksub = lane >> 3;
    const int slot = (wave * 8 + ksub) * 4;
    const int col = (cl >> 1) * 256 + w * 2 + (cl & 1);

    const float* Whh = dir ? whh_b : whh_f;
    const float* Wih = dir ? wih_b : wih_f;
    const float* bias = dir ? bias_b : bias_f;

    float4 wreg[3];
#pragma unroll
    for (int c = 0; c < 3; c++) {
        int k = c * 128 + slot;
        float4 v = make_float4(0.f, 0.f, 0.f, 0.f);
        if (k < 256) v = *(const float4*)&Whh[(size_t)col * 256 + k];
        else if (k - 256 < 80) v = *(const float4*)&Wih[(size_t)col * 80 + (k - 256)];
        wreg[c] = v;
    }
    const float bias_cl = bias[col];

    const int sb = tid >> 3, sk = (tid & 7) * 16;  // staging role
    const int qb = tid >> 1, qj = tid & 1;         // update role (tid<64)
    float c_reg = 0.f;

    unsigned* myflags = flags + dir * 128 * FLAG_STRIDE;
    float* hb_base = hbuf + dir * 2 * 8192;

    for (int t = 0; t < T; t++) {
        const int par = t & 1;
        const int t_act = dir ? (T - 1 - t) : t;
        float* hin = hb_base + par * 8192;

        // issue ALL h loads + x loads up front (overlap IC latency)
        float s0[16], s1[16];
#pragma unroll
        for (int i = 0; i < 16; i++) s0[i] = ld_coh(&hin[sb * 256 + sk + i]);
#pragma unroll
        for (int i = 0; i < 16; i++) s1[i] = ld_coh(&hin[sb * 256 + 128 + sk + i]);
        float4 pf[4];
        if (sk < 80) {
            const float* src = &x[((size_t)sb * 1664 + t_act) * 80 + sk];
#pragma unroll
            for (int i = 0; i < 4; i++) pf[i] = *(const float4*)(src + i * 4);
        } else {
#pragma unroll
            for (int i = 0; i < 4; i++) pf[i] = make_float4(0.f, 0.f, 0.f, 0.f);
        }

#pragma unroll
        for (int i = 0; i < 16; i++) hs[0][sb][sk + i] = s0[i];
        __syncthreads();

        float acc[32];
#pragma unroll
        for (int b = 0; b < 32; b++) acc[b] = 0.f;

#pragma unroll
        for (int c = 0; c < 3; c++) {
            const float* hc = &hs[c & 1][0][0];
            float4 wv = wreg[c];
#pragma unroll
            for (int b = 0; b < 32; b++) {
                float4 hv = *(const float4*)&hc[b * 128 + slot];
                acc[b] = fmaf(hv.x, wv.x, fmaf(hv.y, wv.y, fmaf(hv.z, wv.z, fmaf(hv.w, wv.w, acc[b]))));
            }
            if (c == 0) {
#pragma unroll
                for (int i = 0; i < 16; i++) hs[1][sb][sk + i] = s1[i];
                __syncthreads();
            } else if (c == 1) {
#pragma unroll
                for (int i = 0; i < 4; i++) *(float4*)&hs[0][sb][sk + i * 4] = pf[i];
                __syncthreads();
            }
        }

        // reduce 8 k-slices within wave (lane bits 3..5)
#pragma unroll
        for (int b = 0; b < 32; b++) {
            acc[b] += __shfl_xor(acc[b], 8, 64);
            acc[b] += __shfl_xor(acc[b], 16, 64);
            acc[b] += __shfl_xor(acc[b], 32, 64);
        }
#pragma unroll
        for (int i = 0; i < 4; i++)
            pb[wave][ksub * 4 + i][cl] = acc[ksub * 4 + i];
        __syncthreads();

        // sum 4 waves + bias -> gate value for (b=sb, cl)
        {
            float g = bias_cl;
#pragma unroll
            for (int v = 0; v < 4; v++) g += pb[v][sb][tid & 7];
            gs[sb][tid & 7] = g;
        }
        __syncthreads();

        if (tid < 64) {
            float gi = gs[qb][0 + qj], gf = gs[qb][2 + qj];
            float gg = gs[qb][4 + qj], go = gs[qb][6 + qj];
            float ci = sigmf(gi), cf = sigmf(gf), cg = tanh_(gg), co = sigmf(go);
            c_reg = cf * c_reg + ci * cg;
            float hval = co * tanh_(c_reg);
            st_coh(&hb_base[(par ^ 1) * 8192 + qb * 256 + w * 2 + qj], hval);
            st1g(&out[((size_t)qb * T + t_act) * 512 + dir * 256 + w * 2 + qj], hval);
        }

        step_barrier(myflags, w, tid, (unsigned)(t + 1));
    }
}

// ---------------------------------------------------------------------------
// Pyramid layer (persistent). K = 1280 = 2 h-chunks + 8 input chunks of 128.
// Input chunk c (c>=2): row 2t + ((c-2)>>2), cols ((c-2)*128)&511 .. +128.
// ---------------------------------------------------------------------------
template <typename ST>
__global__ __launch_bounds__(256, 1) void lstm_pyr(
    const ST* __restrict__ in,          // [32][2*Tn][512]
    const float* __restrict__ whh_f, const float* __restrict__ whh_b,  // [1024][256]
    const float* __restrict__ wih_f, const float* __restrict__ wih_b,  // [1024][1024]
    const float* __restrict__ bias_f, const float* __restrict__ bias_b,
    ST* __restrict__ out,               // [32][Tn][512]
    float* __restrict__ hbuf, unsigned* __restrict__ flags, int Tn)
{
    __shared__ __align__(16) float hs[2][32][128];
    __shared__ float pb[4][32][9];
    __shared__ float gs[32][8];

    const int tid = threadIdx.x;
    const int dir = blockIdx.x >> 7;
    const int w = blockIdx.x & 127;
    const int wave = tid >> 6, lane = tid & 63;
    const int cl = lane & 7;
    const int ksub = lane >> 3;
    const int slot = (wave * 8 + ksub) * 4;
    const int col = (cl >> 1) * 256 + w * 2 + (cl & 1);
    const int Tprev = 2 * Tn;

    const float* Whh = dir ? whh_b : whh_f;
    const float* Wih = dir ? wih_b : wih_f;
    const float* bias = dir ? bias_b : bias_f;

    float4 wreg[10];
#pragma unroll
    for (int c = 0; c < 10; c++) {
        int k = c * 128 + slot;
        wreg[c] = (k < 256)
            ? *(const float4*)&Whh[(size_t)col * 256 + k]
            : *(const float4*)&Wih[(size_t)col * 1024 + (k - 256)];
    }
    const float bias_cl = bias[col];

    const int sb = tid >> 3, sk = (tid & 7) * 16;
    const int qb = tid >> 1, qj = tid & 1;
    float c_reg = 0.f;

    unsigned* myflags = flags + dir * 128 * FLAG_STRIDE;
    float* hb_base = hbuf + dir * 2 * 8192;

    for (int t = 0; t < Tn; t++) {
        const int par = t & 1;
        const int t_act = dir ? (Tn - 1 - t) : t;
        float* hin = hb_base + par * 8192;

        // issue BOTH h-chunk coherent load batches up front
        float s0[16], s1[16];
#pragma unroll
        for (int i = 0; i < 16; i++) s0[i] = ld_coh(&hin[sb * 256 + sk + i]);
#pragma unroll
        for (int i = 0; i < 16; i++) s1[i] = ld_coh(&hin[sb * 256 + 128 + sk + i]);
#pragma unroll
        for (int i = 0; i < 16; i++) hs[0][sb][sk + i] = s0[i];
        __syncthreads();

        float acc[32];
#pragma unroll
        for (int b = 0; b < 32; b++) acc[b] = 0.f;

        float4 pf[4];

#pragma unroll
        for (int c = 0; c < 10; c++) {
            // prefetch chunk c+1 (input chunks; h chunk 1 already in s1)
            if (c >= 1 && c < 9) {
                int base = (c - 1) * 128;          // input-k base of chunk c+1
                int r = 2 * t_act + (base >> 9);
                const ST* src = &in[((size_t)sb * Tprev + r) * 512 + (base & 511) + sk];
#pragma unroll
                for (int i = 0; i < 4; i++) pf[i] = ld4g(src + i * 4);
            }
            // compute chunk c
            const float* hc = &hs[c & 1][0][0];
            float4 wv = wreg[c];
#pragma unroll
            for (int b = 0; b < 32; b++) {
                float4 hv = *(const float4*)&hc[b * 128 + slot];
                acc[b] = fmaf(hv.x, wv.x, fmaf(hv.y, wv.y, fmaf(hv.z, wv.z, fmaf(hv.w, wv.w, acc[b]))));
            }
            // commit prefetch into the other buffer
            if (c == 0) {
#pragma unroll
                for (int i = 0; i < 16; i++) hs[1][sb][sk + i] = s1[i];
                __syncthreads();
            } else if (c < 9) {
#pragma unroll
                for (int i = 0; i < 4; i++) *(float4*)&hs[(c + 1) & 1][sb][sk + i * 4] = pf[i];
                __syncthreads();
            }
        }

#pragma unroll
        for (int b = 0; b < 32; b++) {
            acc[b] += __shfl_xor(acc[b], 8, 64);
            acc[b] += __shfl_xor(acc[b], 16, 64);
            acc[b] += __shfl_xor(acc[b], 32, 64);
        }
#pragma unroll
        for (int i = 0; i < 4; i++)
            pb[wave][ksub * 4 + i][cl] = acc[ksub * 4 + i];
        __syncthreads();

        {
            float g = bias_cl;
#pragma unroll
            for (int v = 0; v < 4; v++) g += pb[v][sb][tid & 7];
            gs[sb][tid & 7] = g;
        }
        __syncthreads();

        if (tid < 64) {
            float gi = gs[qb][0 + qj], gf = gs[qb][2 + qj];
            float gg = gs[qb][4 + qj], go = gs[qb][6 + qj];
            float ci = sigmf(gi), cf = sigmf(gf), cg = tanh_(gg), co = sigmf(go);
            c_reg = cf * c_reg + ci * cg;
            float hval = co * tanh_(c_reg);
            st_coh(&hb_base[(par ^ 1) * 8192 + qb * 256 + w * 2 + qj], hval);
            st1g(&out[((size_t)qb * Tn + t_act) * 512 + dir * 256 + w * 2 + qj], hval);
        }

        step_barrier(myflags, w, tid, (unsigned)(t + 1));
    }
}

// ---------------------------------------------------------------------------
// C[M][N] = A[M][K] @ W[N][K]^T + bias  (fp32, 128x128 tiles, 8x8/thread)
// ---------------------------------------------------------------------------
__global__ __launch_bounds__(256) void gemm_bt(
    const float* __restrict__ A, const float* __restrict__ W,
    const float* __restrict__ bias, float* __restrict__ C,
    int M, int N, int K, int ldw)
{
    __shared__ __align__(16) float As[16][128];
    __shared__ __align__(16) float Ws[16][128];
    int tid = threadIdx.x;
    int m0 = blockIdx.x * 128, n0 = blockIdx.y * 128;
    int tx = tid & 15, ty = tid >> 4;

    float acc[8][8];
#pragma unroll
    for (int i = 0; i < 8; i++)
#pragma unroll
        for (int j = 0; j < 8; j++) acc[i][j] = 0.f;

    for (int kb = 0; kb < K; kb += 16) {
#pragma unroll
        for (int l = 0; l < 2; l++) {
            int idx = tid + l * 256;
            int row = idx >> 2, kq = (idx & 3) * 4;
            float4 v = make_float4(0.f, 0.f, 0.f, 0.f);
            if (m0 + row < M)
                v = *(const float4*)&A[(size_t)(m0 + row) * K + kb + kq];
            As[kq + 0][row] = v.x; As[kq + 1][row] = v.y;
            As[kq + 2][row] = v.z; As[kq + 3][row] = v.w;
        }
#pragma unroll
        for (int l = 0; l < 2; l++) {
            int idx = tid + l * 256;
            int row = idx >> 2, kq = (idx & 3) * 4;
            float4 v = *(const float4*)&W[(size_t)(n0 + row) * ldw + kb + kq];
            Ws[kq + 0][row] = v.x; Ws[kq + 1][row] = v.y;
            Ws[kq + 2][row] = v.z; Ws[kq + 3][row] = v.w;
        }
        __syncthreads();
#pragma unroll
        for (int k = 0; k < 16; k++) {
            float a[8], b[8];
            *(float4*)&a[0] = *(const float4*)&As[k][ty * 8];
            *(float4*)&a[4] = *(const float4*)&As[k][ty * 8 + 4];
            *(float4*)&b[0] = *(const float4*)&Ws[k][tx * 8];
            *(float4*)&b[4] = *(const float4*)&Ws[k][tx * 8 + 4];
#pragma unroll
            for (int i = 0; i < 8; i++)
#pragma unroll
                for (int j = 0; j < 8; j++)
                    acc[i][j] = fmaf(a[i], b[j], acc[i][j]);
        }
        __syncthreads();
    }
#pragma unroll
    for (int i = 0; i < 8; i++) {
        int m = m0 + ty * 8 + i;
        if (m >= M) continue;
#pragma unroll
        for (int j = 0; j < 8; j++)
            C[(size_t)m * N + n0 + tx * 8 + j] = acc[i][j] + bias[n0 + tx * 8 + j];
    }
}

__global__ void bf16_to_f32(const __hip_bfloat16* __restrict__ in,
                            float* __restrict__ out, int n)
{
    int i = blockIdx.x * 256 + threadIdx.x;
    if (i < n) out[i] = __bfloat162float(in[i]);
}

// ---------------------------------------------------------------------------
// ctx0 = mean over s of val[b][s][k] -> ctxT [128][32]
// ---------------------------------------------------------------------------
__global__ void ctx0_kernel(const float* __restrict__ val, float* __restrict__ ctxT)
{
    int gid = blockIdx.x * 256 + threadIdx.x;
    if (gid >= 4096) return;
    int k = gid >> 5, b = gid & 31;
    float s = 0.f;
    for (int t = 0; t < 208; t++) s += val[((size_t)b * 208 + t) * 128 + k];
    ctxT[k * 32 + b] = s * (1.0f / 208.0f);
}

// ---------------------------------------------------------------------------
// Decoder cell 1. thread = (h = gid>>5 in [0,512), b = gid&31)
// ---------------------------------------------------------------------------
__global__ __launch_bounds__(256) void dec_cell1(
    const float* __restrict__ table,   // [30][2048] = emb@Wih[:, :256]^T + d1_b
    const int* __restrict__ y,         // [32][200]
    const float* __restrict__ Wih,     // [2048][384]
    const float* __restrict__ Whh,     // [2048][512]
    const float* __restrict__ ctxT_in, // [128][32]
    const float* __restrict__ h1T_in,  // [512][32]
    float* __restrict__ h1T_out,
    float* __restrict__ c1T,
    int t)
{
    int gid = blockIdx.x * 256 + threadIdx.x;
    int h = gid >> 5, b = gid & 31;
    int tok = (t == 0) ? 0 : y[b * 200 + t - 1];

    float acc[4];
#pragma unroll
    for (int g = 0; g < 4; g++) acc[g] = table[tok * 2048 + g * 512 + h];

#pragma unroll 2
    for (int q = 0; q < 32; q++) {
        float hv0 = ctxT_in[(q * 4 + 0) * 32 + b];
        float hv1 = ctxT_in[(q * 4 + 1) * 32 + b];
        float hv2 = ctxT_in[(q * 4 + 2) * 32 + b];
        float hv3 = ctxT_in[(q * 4 + 3) * 32 + b];
#pragma unroll
        for (int g = 0; g < 4; g++) {
            float4 w4 = *(const float4*)&Wih[(size_t)(g * 512 + h) * 384 + 256 + q * 4];
            acc[g] = fmaf(hv0, w4.x, fmaf(hv1, w4.y, fmaf(hv2, w4.z, fmaf(hv3, w4.w, acc[g]))));
        }
    }
#pragma unroll 2
    for (int q = 0; q < 128; q++) {
        float hv0 = h1T_in[(q * 4 + 0) * 32 + b];
        float hv1 = h1T_in[(q * 4 + 1) * 32 + b];
        float hv2 = h1T_in[(q * 4 + 2) * 32 + b];
        float hv3 = h1T_in[(q * 4 + 3) * 32 + b];
#pragma unroll
        for (int g = 0; g < 4; g++) {
            float4 w4 = *(const float4*)&Whh[(size_t)(g * 512 + h) * 512 + q * 4];
            acc[g] = fmaf(hv0, w4.x, fmaf(hv1, w4.y, fmaf(hv2, w4.z, fmaf(hv3, w4.w, acc[g]))));
        }
    }
    float ci = sigmf(acc[0]), cf = sigmf(acc[1]);
    float cg = tanh_(acc[2]), co = sigmf(acc[3]);
    float c = cf * c1T[h * 32 + b] + ci * cg;
    c1T[h * 32 + b] = c;
    h1T_out[h * 32 + b] = co * tanh_(c);
}

// ---------------------------------------------------------------------------
// Decoder cell 2. thread = (h in [0,128), b)
// ---------------------------------------------------------------------------
__global__ __launch_bounds__(256) void dec_cell2(
    const float* __restrict__ Wih,  // [512][512]
    const float* __restrict__ Whh,  // [512][128]
    const float* __restrict__ bias, // [512]
    const float* __restrict__ h1T,
    const float* __restrict__ h2T_in,
    float* __restrict__ h2T_out,
    float* __restrict__ c2T)
{
    int gid = blockIdx.x * 256 + threadIdx.x;
    int h = gid >> 5, b = gid & 31;

    float acc[4];
#pragma unroll
    for (int g = 0; g < 4; g++) acc[g] = bias[g * 128 + h];

#pragma unroll 2
    for (int q = 0; q < 128; q++) {
        float hv0 = h1T[(q * 4 + 0) * 32 + b];
        float hv1 = h1T[(q * 4 + 1) * 32 + b];
        float hv2 = h1T[(q * 4 + 2) * 32 + b];
        float hv3 = h1T[(q * 4 + 3) * 32 + b];
#pragma unroll
        for (int g = 0; g < 4; g++) {
            float4 w4 = *(const float4*)&Wih[(size_t)(g * 128 + h) * 512 + q * 4];
            acc[g] = fmaf(hv0, w4.x, fmaf(hv1, w4.y, fmaf(hv2, w4.z, fmaf(hv3, w4.w, acc[g]))));
        }
    }
#pragma unroll 2
    for (int q = 0; q < 32; q++) {
        float hv0 = h2T_in[(q * 4 + 0) * 32 + b];
        float hv1 = h2T_in[(q * 4 + 1) * 32 + b];
        float hv2 = h2T_in[(q * 4 + 2) * 32 + b];
        float hv3 = h2T_in[(q * 4 + 3) * 32 + b];
#pragma unroll
        for (int g = 0; g < 4; g++) {
            float4 w4 = *(const float4*)&Whh[(size_t)(g * 128 + h) * 128 + q * 4];
            acc[g] = fmaf(hv0, w4.x, fmaf(hv1, w4.y, fmaf(hv2, w4.z, fmaf(hv3, w4.w, acc[g]))));
        }
    }
    float ci = sigmf(acc[0]), cf = sigmf(acc[1]);
    float cg = tanh_(acc[2]), co = sigmf(acc[3]);
    float c = cf * c2T[h * 32 + b] + ci * cg;
    c2T[h * 32 + b] = c;
    h2T_out[h * 32 + b] = co * tanh_(c);
}

// ---------------------------------------------------------------------------
// Attention + logits. grid 32 (one WG per batch) x 256.
// ---------------------------------------------------------------------------
__global__ __launch_bounds__(256) void dec_attend(
    const float* __restrict__ key, const float* __restrict__ val, // [32][208][128]
    const float* __restrict__ h2T,   // [128][32]
    const float* __restrict__ emb,   // [30][256]
    const float* __restrict__ b_out, // [30]
    float* __restrict__ ctxT_out,    // [128][32]
    float* __restrict__ preds,       // [32][200][30]
    float* __restrict__ attn0,       // [200][208]
    int t)
{
    __shared__ __align__(16) float qv[128];
    __shared__ float av[208];
    __shared__ float red[256];
    __shared__ float ctx_s[128];
    int b = blockIdx.x, tid = threadIdx.x;

    if (tid < 128) qv[tid] = h2T[tid * 32 + b];
    __syncthreads();

    float e = -INFINITY;
    if (tid < 208) {
        float s = 0.f;
        const float* kr = key + ((size_t)b * 208 + tid) * 128;
#pragma unroll
        for (int qd = 0; qd < 32; qd++) {
            float4 k4 = *(const float4*)&kr[qd * 4];
            float4 q4 = *(const float4*)&qv[qd * 4];
            s = fmaf(k4.x, q4.x, fmaf(k4.y, q4.y, fmaf(k4.z, q4.z, fmaf(k4.w, q4.w, s))));
        }
        e = s * 0.08838834764831845f;  // 1/sqrt(128)
    }
    red[tid] = e;
    __syncthreads();
    for (int off = 128; off >= 1; off >>= 1) {
        if (tid < off) red[tid] = fmaxf(red[tid], red[tid + off]);
        __syncthreads();
    }
    float m = red[0];
    __syncthreads();
    float ex = (tid < 208) ? __expf(e - m) : 0.f;
    red[tid] = ex;
    __syncthreads();
    for (int off = 128; off >= 1; off >>= 1) {
        if (tid < off) red[tid] += red[tid + off];
        __syncthreads();
    }
    float inv = 1.0f / red[0];
    if (tid < 208) av[tid] = ex * inv;
    __syncthreads();

    if (tid < 128) {
        float s = 0.f;
        for (int ss = 0; ss < 208; ss++)
            s = fmaf(av[ss], val[((size_t)b * 208 + ss) * 128 + tid], s);
        ctx_s[tid] = s;
        ctxT_out[tid * 32 + b] = s;
    }
    __syncthreads();

    if (tid < 30) {
        float s = b_out[tid];
        const float* er = emb + tid * 256;
        for (int k = 0; k < 128; k++) s = fmaf(qv[k], er[k], s);
        for (int k = 0; k < 128; k++) s = fmaf(ctx_s[k], er[128 + k], s);
        preds[((size_t)b * 200 + t) * 30 + tid] = s;
    }
    if (b == 0 && tid < 208) attn0[t * 208 + tid] = av[tid];
}

// ---------------------------------------------------------------------------
template <typename ST>
static void run_encoder(const float* x,
                        const float* e_fw_Wih, const float* e_fw_Whh, const float* e_fw_b,
                        const float* e_bw_Wih, const float* e_bw_Whh, const float* e_bw_b,
                        const float* p_fw_Wih, const float* p_fw_Whh, const float* p_fw_b,
                        const float* p_bw_Wih, const float* p_bw_Whh, const float* p_bw_b,
                        ST* A, ST* B, float* HB, unsigned* FLG, hipStream_t stream)
{
    const unsigned dynLds = 64 * 1024;  // pins 1 WG/CU (static ~38KB + 64KB > 80KB)
    hipMemsetAsync(HB, 0, 32768 * 4, stream);
    hipMemsetAsync(FLG, 0, 2 * 128 * FLAG_STRIDE * 4, stream);
    hipLaunchKernelGGL((lstm_l0<ST>), dim3(256), dim3(256), dynLds, stream,
                       x, e_fw_Whh, e_bw_Whh, e_fw_Wih, e_bw_Wih, e_fw_b, e_bw_b,
                       A, HB, FLG);

    int Ts[3] = {832, 416, 208};
    const ST* ins[3] = {A, B, A};
    ST* outs[3] = {B, A, B};
    for (int L = 0; L < 3; L++) {
        hipMemsetAsync(HB, 0, 32768 * 4, stream);
        hipMemsetAsync(FLG, 0, 2 * 128 * FLAG_STRIDE * 4, stream);
        hipLaunchKernelGGL((lstm_pyr<ST>), dim3(256), dim3(256), dynLds, stream,
                           ins[L],
                           p_fw_Whh + (size_t)L * 1024 * 256, p_bw_Whh + (size_t)L * 1024 * 256,
                           p_fw_Wih + (size_t)L * 1024 * 1024, p_bw_Wih + (size_t)L * 1024 * 1024,
                           p_fw_b + L * 1024, p_bw_b + L * 1024,
                           outs[L], HB, FLG, Ts[L]);
    }
}

extern "C" void kernel_launch(void* const* d_in, const int* in_sizes, int n_in,
                              void* d_out, int out_size, void* d_ws, size_t ws_size,
                              hipStream_t stream)
{
    const float* x        = (const float*)d_in[0];
    // d_in[1] = x_len: constant 1664 -> enc_len = 208 = S (mask is a no-op)
    const int*   y        = (const int*)d_in[2];
    const float* e_fw_Wih = (const float*)d_in[3];
    const float* e_fw_Whh = (const float*)d_in[4];
    const float* e_fw_b   = (const float*)d_in[5];
    const float* e_bw_Wih = (const float*)d_in[6];
    const float* e_bw_Whh = (const float*)d_in[7];
    const float* e_bw_b   = (const float*)d_in[8];
    const float* p_fw_Wih = (const float*)d_in[9];
    const float* p_fw_Whh = (const float*)d_in[10];
    const float* p_fw_b   = (const float*)d_in[11];
    const float* p_bw_Wih = (const float*)d_in[12];
    const float* p_bw_Whh = (const float*)d_in[13];
    const float* p_bw_b   = (const float*)d_in[14];
    const float* Wk       = (const float*)d_in[15];
    const float* bk       = (const float*)d_in[16];
    const float* Wv       = (const float*)d_in[17];
    const float* bv       = (const float*)d_in[18];
    const float* emb      = (const float*)d_in[19];
    const float* d1_Wih   = (const float*)d_in[20];
    const float* d1_Whh   = (const float*)d_in[21];
    const float* d1_b     = (const float*)d_in[22];
    const float* d2_Wih   = (const float*)d_in[23];
    const float* d2_Whh   = (const float*)d_in[24];
    const float* d2_b     = (const float*)d_in[25];
    const float* b_out    = (const float*)d_in[26];

    char* base = (char*)d_ws;
    size_t off = 0;
    auto alloc = [&](size_t bytes) -> void* {
        void* p = base + off;
        off = (off + bytes + 255) & ~(size_t)255;
        return p;
    };

    // misc (both plans)
    float*    KEY = (float*)alloc(851968ull * 4);
    float*    VAL = (float*)alloc(851968ull * 4);
    float*    TBL = (float*)alloc(61440ull * 4);
    float*    HB  = (float*)alloc(32768ull * 4);
    unsigned* FLG = (unsigned*)alloc(2 * 128 * FLAG_STRIDE * 4);
    float*    H1  = (float*)alloc(32768ull * 4);
    float*    H2  = (float*)alloc(8192ull * 4);
    float*    CTX = (float*)alloc(8192ull * 4);
    float*    C1  = (float*)alloc(16384ull * 4);
    float*    C2  = (float*)alloc(4096ull * 4);

    const size_t A_elems = 32ull * 1664 * 512;  // 27,262,976
    const size_t B_elems = 32ull * 832 * 512;   // 13,631,488
    const size_t L3_elems = 32ull * 208 * 512;  //  3,407,872

    size_t misc_end = off;
    size_t need_f32  = misc_end + (A_elems + B_elems) * 4 + 2048;
    size_t need_bf16 = misc_end + L3_elems * 4 + (A_elems + B_elems) * 2 + 2048;

    const float* enc_out;  // fp32 [6656][512] view of final encoder output
    if (ws_size >= need_f32) {
        float* A = (float*)alloc(A_elems * 4);
        float* B = (float*)alloc(B_elems * 4);
        run_encoder<float>(x, e_fw_Wih, e_fw_Whh, e_fw_b, e_bw_Wih, e_bw_Whh, e_bw_b,
                           p_fw_Wih, p_fw_Whh, p_fw_b, p_bw_Wih, p_bw_Whh, p_bw_b,
                           A, B, HB, FLG, stream);
        enc_out = B;
    } else if (ws_size >= need_bf16) {
        float* CONV = (float*)alloc(L3_elems * 4);
        __hip_bfloat16* A = (__hip_bfloat16*)alloc(A_elems * 2);
        __hip_bfloat16* B = (__hip_bfloat16*)alloc(B_elems * 2);
        run_encoder<__hip_bfloat16>(x, e_fw_Wih, e_fw_Whh, e_fw_b, e_bw_Wih, e_bw_Whh, e_bw_b,
                                    p_fw_Wih, p_fw_Whh, p_fw_b, p_bw_Wih, p_bw_Whh, p_bw_b,
                                    A, B, HB, FLG, stream);
        hipLaunchKernelGGL(bf16_to_f32, dim3((unsigned)(L3_elems / 256)), dim3(256), 0, stream,
                           B, CONV, (int)L3_elems);
        enc_out = CONV;
    } else {
        return;  // workspace too small for any plan
    }

    // ---- key / val projections + decoder precompute ----
    hipLaunchKernelGGL(gemm_bt, dim3(52, 1), dim3(256), 0, stream,
                       enc_out, Wk, bk, KEY, 6656, 128, 512, 512);
    hipLaunchKernelGGL(gemm_bt, dim3(52, 1), dim3(256), 0, stream,
                       enc_out, Wv, bv, VAL, 6656, 128, 512, 512);
    hipLaunchKernelGGL(gemm_bt, dim3(1, 16), dim3(256), 0, stream,
                       emb, d1_Wih, d1_b, TBL, 30, 2048, 256, 384);
    hipLaunchKernelGGL(ctx0_kernel, dim3(16), dim3(256), 0, stream, VAL, CTX);
    hipMemsetAsync(H1, 0, 32768 * 4, stream);
    hipMemsetAsync(H2, 0, 8192 * 4, stream);
    hipMemsetAsync(C1, 0, 16384 * 4, stream);
    hipMemsetAsync(C2, 0, 4096 * 4, stream);

    float* preds = (float*)d_out;
    float* attn0 = (float*)d_out + 192000;

    for (int t = 0; t < 200; t++) {
        float* h1i = H1 + (t & 1) * 16384;
        float* h1o = H1 + ((t + 1) & 1) * 16384;
        float* h2i = H2 + (t & 1) * 4096;
        float* h2o = H2 + ((t + 1) & 1) * 4096;
        float* cxi = CTX + (t & 1) * 4096;
        float* cxo = CTX + ((t + 1) & 1) * 4096;
        hipLaunchKernelGGL(dec_cell1, dim3(64), dim3(256), 0, stream,
                           TBL, y, d1_Wih, d1_Whh, cxi, h1i, h1o, C1, t);
        hipLaunchKernelGGL(dec_cell2, dim3(16), dim3(256), 0, stream,
                           d2_Wih, d2_Whh, d2_b, h1o, h2i, h2o, C2);
        hipLaunchKernelGGL(dec_attend, dim3(32), dim3(256), 0, stream,
                           KEY, VAL, h2o, emb, b_out, cxo, preds, attn0, t);
    }
}

// Round 6
// 44852.029 us; speedup vs baseline: 2.3399x; 1.1972x over previous
//
#include <hip/hip_runtime.h>
#include <hip/hip_bf16.h>
#include <math.h>
#include <stdint.h>

// Seq2Seq LAS model. B=32, T=1664, F_IN=80, H_ENC=256, KV=128, D_DEC=512,
// EMB=256, VOCAB=30, L=200.
// R6 encoder: the h-exchange is restructured to minimize L3/IC transactions:
//  - hbuf is unit-major [dir][par][256][32]: each WG's 64 h-stores land in
//    exactly 2 full 128B lines (R5: 32 partial 8B-line writes).
//  - h reload: 16x 8B coherent loads/thread (__hip_atomic_load u64 ->
//    global_load_dwordx2 sc0 sc1), contiguous across lanes: ~128 line
//    transactions per WG vs R5's 4096 scalar 4B L3 round trips (L1/L2
//    bypassed => no line reuse). Then LDS transpose.
//  - K-loop consolidated: 6 syncthreads/step (pyr), 3 (l0).
// Barrier mechanism (monotonic strided flags, relaxed agent atomics),
// decoder, and GEMMs unchanged from R5 (controlled variables).

#define DEV __device__ __forceinline__

#define FLAG_STRIDE 16  // dwords; one flag per 64B line

DEV float sigmf(float x) { return 1.0f / (1.0f + __expf(-x)); }
DEV float tanh_(float x) { return 1.0f - 2.0f / (__expf(2.0f * x) + 1.0f); }

struct __align__(8) bf4 { __hip_bfloat16 a, b, c, d; };

DEV float4 ld4g(const float* p) { return *(const float4*)p; }
DEV float4 ld4g(const __hip_bfloat16* p) {
    bf4 v = *(const bf4*)p;
    return make_float4(__bfloat162float(v.a), __bfloat162float(v.b),
                       __bfloat162float(v.c), __bfloat162float(v.d));
}
DEV void st1g(float* p, float v) { *p = v; }
DEV void st1g(__hip_bfloat16* p, float v) { *p = __float2bfloat16(v); }

DEV void st_coh(float* p, float v) {
    __hip_atomic_store(p, v, __ATOMIC_RELAXED, __HIP_MEMORY_SCOPE_AGENT);
}
DEV unsigned long long ld_coh64(const unsigned long long* p) {
    return __hip_atomic_load(p, __ATOMIC_RELAXED, __HIP_MEMORY_SCOPE_AGENT);
}

extern __shared__ float dyn_pad[];  // launch-time pad to pin 1 WG/CU (l0)

// ---------------------------------------------------------------------------
// step barrier among 128 WGs of one direction. Flags strided 64B apart.
// __syncthreads drains vmcnt (coherent h-stores visible) before flag store.
// ---------------------------------------------------------------------------
DEV void step_barrier(unsigned* myflags, int w, int tid, unsigned tv)
{
    __syncthreads();
    if (tid == 0)
        __hip_atomic_store(&myflags[w * FLAG_STRIDE], tv, __ATOMIC_RELAXED,
                           __HIP_MEMORY_SCOPE_AGENT);
    if (tid < 128) {
        int guard = 0;
        while (__hip_atomic_load(&myflags[tid * FLAG_STRIDE], __ATOMIC_RELAXED,
                                 __HIP_MEMORY_SCOPE_AGENT) < tv) {
            __builtin_amdgcn_s_sleep(1);
            if (++guard > (1 << 15)) break;  // anti-hang: fail loud, not forever
        }
    }
    __syncthreads();
}

// ---------------------------------------------------------------------------
// Encoder layer 0 (persistent). grid 256: dir=blk>>7, w=blk&127 (units 2w,2w+1).
// hbuf unit-major: [dir][parity][256][32]; flags: [dir][128*FLAG_STRIDE].
// LDS hs[32][388]: cols 0..255 = h, 256..335 = x_t, 336..387 zeroed (weights
// for k>=336 are 0, so the padded dot contributes nothing).
// ---------------------------------------------------------------------------
template <typename ST>
__global__ __launch_bounds__(256, 1) void lstm_l0(
    const float* __restrict__ x,        // [32][1664][80]
    const float* __restrict__ whh_f, const float* __restrict__ whh_b,  // [1024][256]
    const float* __restrict__ wih_f, const float* __restrict__ wih_b,  // [1024][80]
    const float* __restrict__ bias_f, const float* __restrict__ bias_b,
    ST* __restrict__ out,               // [32][1664][512]
    float* __restrict__ hbuf, unsigned* __restrict__ flags)
{
    const int T = 1664;
    const int RS = 388;  // hs row stride (4-aligned; 4-way bank alias on transpose)
    __shared__ __align__(16) float hs[32 * 388];
    __shared__ float pb[4][32][9];
    __shared__ float gs[32][8];

    const int tid = threadIdx.x;
    const int dir = blockIdx.x >> 7;
    const int w = blockIdx.x & 127;
    const int wave = tid >> 6, lane = tid & 63;
    const int cl = lane & 7;
    const int ksub = lane >> 3;
    const int slot = (wave * 8 + ksub) * 4;
    const int col = (cl >> 1) * 256 + w * 2 + (cl & 1);

    const float* Whh = dir ? whh_b : whh_f;
    const float* Wih = dir ? wih_b : wih_f;
    const float* bias = dir ? bias_b : bias_f;

    float4 wreg[3];
#pragma unroll
    for (int c = 0; c < 3; c++) {
        int k = c * 128 + slot;
        float4 v = make_float4(0.f, 0.f, 0.f, 0.f);
        if (k < 256) v = *(const float4*)&Whh[(size_t)col * 256 + k];
        else if (k - 256 < 80) v = *(const float4*)&Wih[(size_t)col * 80 + (k - 256)];
        wreg[c] = v;
    }
    const float bias_cl = bias[col];

    const int qb = tid >> 1, qj = tid & 1;  // update role (tid<64)
    float c_reg = 0.f;

    unsigned* myflags = flags + dir * 128 * FLAG_STRIDE;
    float* hb_base = hbuf + dir * 2 * 8192;

    // zero the pad region (cols 336..387) once: garbage here would be ok
    // numerically (x0 weights) only if finite; LDS init is undefined.
    for (int i = tid; i < 32 * 52; i += 256)
        hs[(i / 52) * RS + 336 + (i % 52)] = 0.f;

    for (int t = 0; t < T; t++) {
        const int par = t & 1;
        const int t_act = dir ? (T - 1 - t) : t;
        const unsigned long long* h64 =
            (const unsigned long long*)(hb_base + par * 8192);

        // ---- coherent wide h reload (16 x 8B per thread, lane-contiguous) ----
        unsigned long long hv64[16];
#pragma unroll
        for (int j = 0; j < 16; j++)
            hv64[j] = ld_coh64(&h64[tid + j * 256]);
        // x_t loads (plain, L1/L2-cached)
        float4 xf[3];
        int xn = 0;
        for (int i4 = tid; i4 < 640; i4 += 256) {
            int e = i4 * 4;
            xf[xn++] = *(const float4*)&x[((size_t)(e / 80) * 1664 + t_act) * 80 + (e % 80)];
        }
        // LDS transpose commit: u64 q -> unit u=q>>4, batches b0,b0+1
#pragma unroll
        for (int j = 0; j < 16; j++) {
            int q = tid + j * 256;
            int u = q >> 4, b0 = (q & 15) * 2;
            hs[b0 * RS + u] = __uint_as_float((unsigned)hv64[j]);
            hs[(b0 + 1) * RS + u] = __uint_as_float((unsigned)(hv64[j] >> 32));
        }
        xn = 0;
        for (int i4 = tid; i4 < 640; i4 += 256) {
            int e = i4 * 4;
            *(float4*)&hs[(e / 80) * RS + 256 + (e % 80)] = xf[xn++];
        }
        __syncthreads();  // S1

        float acc[32];
#pragma unroll
        for (int b = 0; b < 32; b++) acc[b] = 0.f;
#pragma unroll
        for (int c = 0; c < 3; c++) {
            float4 wv = wreg[c];
            const float* src = &hs[c * 128 + slot];
#pragma unroll
            for (int b = 0; b < 32; b++) {
                float4 hv = *(const float4*)&src[b * RS];
                acc[b] = fmaf(hv.x, wv.x, fmaf(hv.y, wv.y, fmaf(hv.z, wv.z, fmaf(hv.w, wv.w, acc[b]))));
            }
        }

        // reduce 8 k-slices within wave (lane bits 3..5)
#pragma unroll
        for (int b = 0; b < 32; b++) {
            acc[b] += __shfl_xor(acc[b], 8, 64);
            acc[b] += __shfl_xor(acc[b], 16, 64);
            acc[b] += __shfl_xor(acc[b], 32, 64);
        }
#pragma unroll
        for (int i = 0; i < 4; i++)
            pb[wave][ksub * 4 + i][cl] = acc[ksub * 4 + i];
        __syncthreads();  // S2

        {
            int sb = tid >> 3;
            float g = bias_cl;
#pragma unroll
            for (int v = 0; v < 4; v++) g += pb[v][sb][tid & 7];
            gs[sb][tid & 7] = g;
        }
        __syncthreads();  // S3

        if (tid < 64) {
            float gi = gs[qb][0 + qj], gf = gs[qb][2 + qj];
            float gg = gs[qb][4 + qj], go = gs[qb][6 + qj];
            float ci = sigmf(gi), cf = sigmf(gf), cg = tanh_(gg), co = sigmf(go);
            c_reg = cf * c_reg + ci * cg;
            float hval = co * tanh_(c_reg);
            // unit-major store: 64 lanes cover 2 full 128B lines
            st_coh(&hb_base[(par ^ 1) * 8192 + (w * 2 + qj) * 32 + qb], hval);
            st1g(&out[((size_t)qb * T + t_act) * 512 + dir * 256 + w * 2 + qj], hval);
        }

        step_barrier(myflags, w, tid, (unsigned)(t + 1));
    }
}

// ---------------------------------------------------------------------------
// Pyramid layer (persistent). K = 1280 = 256 h (resident hsh) + 4 in-groups
// of 256 (ping-pong is[2]). 6 syncthreads/step.
// in-group g: row 2t+(g>>1), cols (g&1)*256..+255.
// ---------------------------------------------------------------------------
template <typename ST>
__global__ __launch_bounds__(256, 1) void lstm_pyr(
    const ST* __restrict__ in,          // [32][2*Tn][512]
    const float* __restrict__ whh_f, const float* __restrict__ whh_b,  // [1024][256]
    const float* __restrict__ wih_f, const float* __restrict__ wih_b,  // [1024][1024]
    const float* __restrict__ bias_f, const float* __restrict__ bias_b,
    ST* __restrict__ out,               // [32][Tn][512]
    float* __restrict__ hbuf, unsigned* __restrict__ flags, int Tn)
{
    const int RS = 260;  // row stride (4-aligned)
    __shared__ __align__(16) float hsh[32 * 260];
    __shared__ __align__(16) float is[2][32 * 260];
    __shared__ float pb[4][32][9];
    __shared__ float gs[32][8];

    const int tid = threadIdx.x;
    const int dir = blockIdx.x >> 7;
    const int w = blockIdx.x & 127;
    const int wave = tid >> 6, lane = tid & 63;
    const int cl = lane & 7;
    const int ksub = lane >> 3;
    const int slot = (wave * 8 + ksub) * 4;
    const int col = (cl >> 1) * 256 + w * 2 + (cl & 1);
    const int Tprev = 2 * Tn;

    const float* Whh = dir ? whh_b : whh_f;
    const float* Wih = dir ? wih_b : wih_f;
    const float* bias = dir ? bias_b : bias_f;

    float4 wreg[10];
#pragma unroll
    for (int c = 0; c < 10; c++) {
        int k = c * 128 + slot;
        wreg[c] = (k < 256)
            ? *(const float4*)&Whh[(size_t)col * 256 + k]
            : *(const float4*)&Wih[(size_t)col * 1024 + (k - 256)];
    }
    const float bias_cl = bias[col];

    const int sb = tid >> 3, sk = (tid & 7) * 32;  // in-staging role
    const int qb = tid >> 1, qj = tid & 1;
    float c_reg = 0.f;

    unsigned* myflags = flags + dir * 128 * FLAG_STRIDE;
    float* hb_base = hbuf + dir * 2 * 8192;

    for (int t = 0; t < Tn; t++) {
        const int par = t & 1;
        const int t_act = dir ? (Tn - 1 - t) : t;
        const unsigned long long* h64 =
            (const unsigned long long*)(hb_base + par * 8192);

        float acc[32];
#pragma unroll
        for (int b = 0; b < 32; b++) acc[b] = 0.f;

        // helper: load in-group g into registers
        float4 gbuf[8];
        auto load_grp = [&](int g) {
            int r = 2 * t_act + (g >> 1);
            int cb = (g & 1) * 256;
            const ST* src = &in[((size_t)sb * Tprev + r) * 512 + cb + sk];
#pragma unroll
            for (int i = 0; i < 8; i++) gbuf[i] = ld4g(src + i * 4);
        };
        auto commit_grp = [&](int buf) {
#pragma unroll
            for (int i = 0; i < 8; i++)
                *(float4*)&is[buf][sb * RS + sk + i * 4] = gbuf[i];
        };
        auto dot2 = [&](const float* base, int wi) {
#pragma unroll
            for (int cc = 0; cc < 2; cc++) {
                float4 wv = wreg[wi + cc];
                const float* src = base + cc * 128 + slot;
#pragma unroll
                for (int b = 0; b < 32; b++) {
                    float4 hv = *(const float4*)&src[b * RS];
                    acc[b] = fmaf(hv.x, wv.x, fmaf(hv.y, wv.y, fmaf(hv.z, wv.z, fmaf(hv.w, wv.w, acc[b]))));
                }
            }
        };

        // ---- coherent wide h reload + group 0 ----
        unsigned long long hv64[16];
#pragma unroll
        for (int j = 0; j < 16; j++)
            hv64[j] = ld_coh64(&h64[tid + j * 256]);
        load_grp(0);
#pragma unroll
        for (int j = 0; j < 16; j++) {
            int q = tid + j * 256;
            int u = q >> 4, b0 = (q & 15) * 2;
            hsh[b0 * RS + u] = __uint_as_float((unsigned)hv64[j]);
            hsh[(b0 + 1) * RS + u] = __uint_as_float((unsigned)(hv64[j] >> 32));
        }
        commit_grp(0);  // -> is[0]
        __syncthreads();  // S1

        load_grp(1);
        dot2(&hsh[slot - slot], 0);   // h chunks c0,c1 (base hsh)
        dot2(&is[0][0], 2);           // c2,c3
        commit_grp(1);  // -> is[1]
        __syncthreads();  // S2

        load_grp(2);
        dot2(&is[1][0], 4);           // c4,c5
        commit_grp(0);  // -> is[0]
        __syncthreads();  // S3

        load_grp(3);
        dot2(&is[0][0], 6);           // c6,c7
        commit_grp(1);  // -> is[1]
        __syncthreads();  // S4

        dot2(&is[1][0], 8);           // c8,c9

#pragma unroll
        for (int b = 0; b < 32; b++) {
            acc[b] += __shfl_xor(acc[b], 8, 64);
            acc[b] += __shfl_xor(acc[b], 16, 64);
            acc[b] += __shfl_xor(acc[b], 32, 64);
        }
#pragma unroll
        for (int i = 0; i < 4; i++)
            pb[wave][ksub * 4 + i][cl] = acc[ksub * 4 + i];
        __syncthreads();  // S5

        {
            float g = bias_cl;
#pragma unroll
            for (int v = 0; v < 4; v++) g += pb[v][sb][tid & 7];
            gs[sb][tid & 7] = g;
        }
        __syncthreads();  // S6

        if (tid < 64) {
            float gi = gs[qb][0 + qj], gf = gs[qb][2 + qj];
            float gg = gs[qb][4 + qj], go = gs[qb][6 + qj];
            float ci = sigmf(gi), cf = sigmf(gf), cg = tanh_(gg), co = sigmf(go);
            c_reg = cf * c_reg + ci * cg;
            float hval = co * tanh_(c_reg);
            st_coh(&hb_base[(par ^ 1) * 8192 + (w * 2 + qj) * 32 + qb], hval);
            st1g(&out[((size_t)qb * Tn + t_act) * 512 + dir * 256 + w * 2 + qj], hval);
        }

        step_barrier(myflags, w, tid, (unsigned)(t + 1));
    }
}

// ---------------------------------------------------------------------------
// C[M][N] = A[M][K] @ W[N][K]^T + bias  (fp32, 128x128 tiles, 8x8/thread)
// ---------------------------------------------------------------------------
__global__ __launch_bounds__(256) void gemm_bt(
    const float* __restrict__ A, const float* __restrict__ W,
    const float* __restrict__ bias, float* __restrict__ C,
    int M, int N, int K, int ldw)
{
    __shared__ __align__(16) float As[16][128];
    __shared__ __align__(16) float Ws[16][128];
    int tid = threadIdx.x;
    int m0 = blockIdx.x * 128, n0 = blockIdx.y * 128;
    int tx = tid & 15, ty = tid >> 4;

    float acc[8][8];
#pragma unroll
    for (int i = 0; i < 8; i++)
#pragma unroll
        for (int j = 0; j < 8; j++) acc[i][j] = 0.f;

    for (int kb = 0; kb < K; kb += 16) {
#pragma unroll
        for (int l = 0; l < 2; l++) {
            int idx = tid + l * 256;
            int row = idx >> 2, kq = (idx & 3) * 4;
            float4 v = make_float4(0.f, 0.f, 0.f, 0.f);
            if (m0 + row < M)
                v = *(const float4*)&A[(size_t)(m0 + row) * K + kb + kq];
            As[kq + 0][row] = v.x; As[kq + 1][row] = v.y;
            As[kq + 2][row] = v.z; As[kq + 3][row] = v.w;
        }
#pragma unroll
        for (int l = 0; l < 2; l++) {
            int idx = tid + l * 256;
            int row = idx >> 2, kq = (idx & 3) * 4;
            float4 v = *(const float4*)&W[(size_t)(n0 + row) * ldw + kb + kq];
            Ws[kq + 0][row] = v.x; Ws[kq + 1][row] = v.y;
            Ws[kq + 2][row] = v.z; Ws[kq + 3][row] = v.w;
        }
        __syncthreads();
#pragma unroll
        for (int k = 0; k < 16; k++) {
            float a[8], b[8];
            *(float4*)&a[0] = *(const float4*)&As[k][ty * 8];
            *(float4*)&a[4] = *(const float4*)&As[k][ty * 8 + 4];
            *(float4*)&b[0] = *(const float4*)&Ws[k][tx * 8];
            *(float4*)&b[4] = *(const float4*)&Ws[k][tx * 8 + 4];
#pragma unroll
            for (int i = 0; i < 8; i++)
#pragma unroll
                for (int j = 0; j < 8; j++)
                    acc[i][j] = fmaf(a[i], b[j], acc[i][j]);
        }
        __syncthreads();
    }
#pragma unroll
    for (int i = 0; i < 8; i++) {
        int m = m0 + ty * 8 + i;
        if (m >= M) continue;
#pragma unroll
        for (int j = 0; j < 8; j++)
            C[(size_t)m * N + n0 + tx * 8 + j] = acc[i][j] + bias[n0 + tx * 8 + j];
    }
}

__global__ void bf16_to_f32(const __hip_bfloat16* __restrict__ in,
                            float* __restrict__ out, int n)
{
    int i = blockIdx.x * 256 + threadIdx.x;
    if (i < n) out[i] = __bfloat162float(in[i]);
}

// ---------------------------------------------------------------------------
// ctx0 = mean over s of val[b][s][k] -> ctxT [128][32]
// ---------------------------------------------------------------------------
__global__ void ctx0_kernel(const float* __restrict__ val, float* __restrict__ ctxT)
{
    int gid = blockIdx.x * 256 + threadIdx.x;
    if (gid >= 4096) return;
    int k = gid >> 5, b = gid & 31;
    float s = 0.f;
    for (int t = 0; t < 208; t++) s += val[((size_t)b * 208 + t) * 128 + k];
    ctxT[k * 32 + b] = s * (1.0f / 208.0f);
}

// ---------------------------------------------------------------------------
// Decoder cell 1. thread = (h = gid>>5 in [0,512), b = gid&31)
// ---------------------------------------------------------------------------
__global__ __launch_bounds__(256) void dec_cell1(
    const float* __restrict__ table,   // [30][2048] = emb@Wih[:, :256]^T + d1_b
    const int* __restrict__ y,         // [32][200]
    const float* __restrict__ Wih,     // [2048][384]
    const float* __restrict__ Whh,     // [2048][512]
    const float* __restrict__ ctxT_in, // [128][32]
    const float* __restrict__ h1T_in,  // [512][32]
    float* __restrict__ h1T_out,
    float* __restrict__ c1T,
    int t)
{
    int gid = blockIdx.x * 256 + threadIdx.x;
    int h = gid >> 5, b = gid & 31;
    int tok = (t == 0) ? 0 : y[b * 200 + t - 1];

    float acc[4];
#pragma unroll
    for (int g = 0; g < 4; g++) acc[g] = table[tok * 2048 + g * 512 + h];

#pragma unroll 2
    for (int q = 0; q < 32; q++) {
        float hv0 = ctxT_in[(q * 4 + 0) * 32 + b];
        float hv1 = ctxT_in[(q * 4 + 1) * 32 + b];
        float hv2 = ctxT_in[(q * 4 + 2) * 32 + b];
        float hv3 = ctxT_in[(q * 4 + 3) * 32 + b];
#pragma unroll
        for (int g = 0; g < 4; g++) {
            float4 w4 = *(const float4*)&Wih[(size_t)(g * 512 + h) * 384 + 256 + q * 4];
            acc[g] = fmaf(hv0, w4.x, fmaf(hv1, w4.y, fmaf(hv2, w4.z, fmaf(hv3, w4.w, acc[g]))));
        }
    }
#pragma unroll 2
    for (int q = 0; q < 128; q++) {
        float hv0 = h1T_in[(q * 4 + 0) * 32 + b];
        float hv1 = h1T_in[(q * 4 + 1) * 32 + b];
        float hv2 = h1T_in[(q * 4 + 2) * 32 + b];
        float hv3 = h1T_in[(q * 4 + 3) * 32 + b];
#pragma unroll
        for (int g = 0; g < 4; g++) {
            float4 w4 = *(const float4*)&Whh[(size_t)(g * 512 + h) * 512 + q * 4];
            acc[g] = fmaf(hv0, w4.x, fmaf(hv1, w4.y, fmaf(hv2, w4.z, fmaf(hv3, w4.w, acc[g]))));
        }
    }
    float ci = sigmf(acc[0]), cf = sigmf(acc[1]);
    float cg = tanh_(acc[2]), co = sigmf(acc[3]);
    float c = cf * c1T[h * 32 + b] + ci * cg;
    c1T[h * 32 + b] = c;
    h1T_out[h * 32 + b] = co * tanh_(c);
}

// ---------------------------------------------------------------------------
// Decoder cell 2. thread = (h in [0,128), b)
// ---------------------------------------------------------------------------
__global__ __launch_bounds__(256) void dec_cell2(
    const float* __restrict__ Wih,  // [512][512]
    const float* __restrict__ Whh,  // [512][128]
    const float* __restrict__ bias, // [512]
    const float* __restrict__ h1T,
    const float* __restrict__ h2T_in,
    float* __restrict__ h2T_out,
    float* __restrict__ c2T)
{
    int gid = blockIdx.x * 256 + threadIdx.x;
    int h = gid >> 5, b = gid & 31;

    float acc[4];
#pragma unroll
    for (int g = 0; g < 4; g++) acc[g] = bias[g * 128 + h];

#pragma unroll 2
    for (int q = 0; q < 128; q++) {
        float hv0 = h1T[(q * 4 + 0) * 32 + b];
        float hv1 = h1T[(q * 4 + 1) * 32 + b];
        float hv2 = h1T[(q * 4 + 2) * 32 + b];
        float hv3 = h1T[(q * 4 + 3) * 32 + b];
#pragma unroll
        for (int g = 0; g < 4; g++) {
            float4 w4 = *(const float4*)&Wih[(size_t)(g * 128 + h) * 512 + q * 4];
            acc[g] = fmaf(hv0, w4.x, fmaf(hv1, w4.y, fmaf(hv2, w4.z, fmaf(hv3, w4.w, acc[g]))));
        }
    }
#pragma unroll 2
    for (int q = 0; q < 32; q++) {
        float hv0 = h2T_in[(q * 4 + 0) * 32 + b];
        float hv1 = h2T_in[(q * 4 + 1) * 32 + b];
        float hv2 = h2T_in[(q * 4 + 2) * 32 + b];
        float hv3 = h2T_in[(q * 4 + 3) * 32 + b];
#pragma unroll
        for (int g = 0; g < 4; g++) {
            float4 w4 = *(const float4*)&Whh[(size_t)(g * 128 + h) * 128 + q * 4];
            acc[g] = fmaf(hv0, w4.x, fmaf(hv1, w4.y, fmaf(hv2, w4.z, fmaf(hv3, w4.w, acc[g]))));
        }
    }
    float ci = sigmf(acc[0]), cf = sigmf(acc[1]);
    float cg = tanh_(acc[2]), co = sigmf(acc[3]);
    float c = cf * c2T[h * 32 + b] + ci * cg;
    c2T[h * 32 + b] = c;
    h2T_out[h * 32 + b] = co * tanh_(c);
}

// ---------------------------------------------------------------------------
// Attention + logits. grid 32 (one WG per batch) x 256.
// ---------------------------------------------------------------------------
__global__ __launch_bounds__(256) void dec_attend(
    const float* __restrict__ key, const float* __restrict__ val, // [32][208][128]
    const float* __restrict__ h2T,   // [128][32]
    const float* __restrict__ emb,   // [30][256]
    const float* __restrict__ b_out, // [30]
    float* __restrict__ ctxT_out,    // [128][32]
    float* __restrict__ preds,       // [32][200][30]
    float* __restrict__ attn0,       // [200][208]
    int t)
{
    __shared__ __align__(16) float qv[128];
    __shared__ float av[208];
    __shared__ float red[256];
    __shared__ float ctx_s[128];
    int b = blockIdx.x, tid = threadIdx.x;

    if (tid < 128) qv[tid] = h2T[tid * 32 + b];
    __syncthreads();

    float e = -INFINITY;
    if (tid < 208) {
        float s = 0.f;
        const float* kr = key + ((size_t)b * 208 + tid) * 128;
#pragma unroll
        for (int qd = 0; qd < 32; qd++) {
            float4 k4 = *(const float4*)&kr[qd * 4];
            float4 q4 = *(const float4*)&qv[qd * 4];
            s = fmaf(k4.x, q4.x, fmaf(k4.y, q4.y, fmaf(k4.z, q4.z, fmaf(k4.w, q4.w, s))));
        }
        e = s * 0.08838834764831845f;  // 1/sqrt(128)
    }
    red[tid] = e;
    __syncthreads();
    for (int off = 128; off >= 1; off >>= 1) {
        if (tid < off) red[tid] = fmaxf(red[tid], red[tid + off]);
        __syncthreads();
    }
    float m = red[0];
    __syncthreads();
    float ex = (tid < 208) ? __expf(e - m) : 0.f;
    red[tid] = ex;
    __syncthreads();
    for (int off = 128; off >= 1; off >>= 1) {
        if (tid < off) red[tid] += red[tid + off];
        __syncthreads();
    }
    float inv = 1.0f / red[0];
    if (tid < 208) av[tid] = ex * inv;
    __syncthreads();

    if (tid < 128) {
        float s = 0.f;
        for (int ss = 0; ss < 208; ss++)
            s = fmaf(av[ss], val[((size_t)b * 208 + ss) * 128 + tid], s);
        ctx_s[tid] = s;
        ctxT_out[tid * 32 + b] = s;
    }
    __syncthreads();

    if (tid < 30) {
        float s = b_out[tid];
        const float* er = emb + tid * 256;
        for (int k = 0; k < 128; k++) s = fmaf(qv[k], er[k], s);
        for (int k = 0; k < 128; k++) s = fmaf(ctx_s[k], er[128 + k], s);
        preds[((size_t)b * 200 + t) * 30 + tid] = s;
    }
    if (b == 0 && tid < 208) attn0[t * 208 + tid] = av[tid];
}

// ---------------------------------------------------------------------------
template <typename ST>
static void run_encoder(const float* x,
                        const float* e_fw_Wih, const float* e_fw_Whh, const float* e_fw_b,
                        const float* e_bw_Wih, const float* e_bw_Whh, const float* e_bw_b,
                        const float* p_fw_Wih, const float* p_fw_Whh, const float* p_fw_b,
                        const float* p_bw_Wih, const float* p_bw_Whh, const float* p_bw_b,
                        ST* A, ST* B, float* HB, unsigned* FLG, hipStream_t stream)
{
    hipMemsetAsync(HB, 0, 32768 * 4, stream);
    hipMemsetAsync(FLG, 0, 2 * 128 * FLAG_STRIDE * 4, stream);
    // l0: static LDS ~55KB + 32KB dyn pad -> 1 WG/CU (all 256 co-resident)
    hipLaunchKernelGGL((lstm_l0<ST>), dim3(256), dim3(256), 32 * 1024, stream,
                       x, e_fw_Whh, e_bw_Whh, e_fw_Wih, e_bw_Wih, e_fw_b, e_bw_b,
                       A, HB, FLG);

    int Ts[3] = {832, 416, 208};
    const ST* ins[3] = {A, B, A};
    ST* outs[3] = {B, A, B};
    for (int L = 0; L < 3; L++) {
        hipMemsetAsync(HB, 0, 32768 * 4, stream);
        hipMemsetAsync(FLG, 0, 2 * 128 * FLAG_STRIDE * 4, stream);
        // pyr: static LDS ~105KB -> 1 WG/CU naturally
        hipLaunchKernelGGL((lstm_pyr<ST>), dim3(256), dim3(256), 0, stream,
                           ins[L],
                           p_fw_Whh + (size_t)L * 1024 * 256, p_bw_Whh + (size_t)L * 1024 * 256,
                           p_fw_Wih + (size_t)L * 1024 * 1024, p_bw_Wih + (size_t)L * 1024 * 1024,
                           p_fw_b + L * 1024, p_bw_b + L * 1024,
                           outs[L], HB, FLG, Ts[L]);
    }
}

extern "C" void kernel_launch(void* const* d_in, const int* in_sizes, int n_in,
                              void* d_out, int out_size, void* d_ws, size_t ws_size,
                              hipStream_t stream)
{
    const float* x        = (const float*)d_in[0];
    // d_in[1] = x_len: constant 1664 -> enc_len = 208 = S (mask is a no-op)
    const int*   y        = (const int*)d_in[2];
    const float* e_fw_Wih = (const float*)d_in[3];
    const float* e_fw_Whh = (const float*)d_in[4];
    const float* e_fw_b   = (const float*)d_in[5];
    const float* e_bw_Wih = (const float*)d_in[6];
    const float* e_bw_Whh = (const float*)d_in[7];
    const float* e_bw_b   = (const float*)d_in[8];
    const float* p_fw_Wih = (const float*)d_in[9];
    const float* p_fw_Whh = (const float*)d_in[10];
    const float* p_fw_b   = (const float*)d_in[11];
    const float* p_bw_Wih = (const float*)d_in[12];
    const float* p_bw_Whh = (const float*)d_in[13];
    const float* p_bw_b   = (const float*)d_in[14];
    const float* Wk       = (const float*)d_in[15];
    const float* bk       = (const float*)d_in[16];
    const float* Wv       = (const float*)d_in[17];
    const float* bv       = (const float*)d_in[18];
    const float* emb      = (const float*)d_in[19];
    const float* d1_Wih   = (const float*)d_in[20];
    const float* d1_Whh   = (const float*)d_in[21];
    const float* d1_b     = (const float*)d_in[22];
    const float* d2_Wih   = (const float*)d_in[23];
    const float* d2_Whh   = (const float*)d_in[24];
    const float* d2_b     = (const float*)d_in[25];
    const float* b_out    = (const float*)d_in[26];

    char* base = (char*)d_ws;
    size_t off = 0;
    auto alloc = [&](size_t bytes) -> void* {
        void* p = base + off;
        off = (off + bytes + 255) & ~(size_t)255;
        return p;
    };

    // misc (both plans)
    float*    KEY = (float*)alloc(851968ull * 4);
    float*    VAL = (float*)alloc(851968ull * 4);
    float*    TBL = (float*)alloc(61440ull * 4);
    float*    HB  = (float*)alloc(32768ull * 4);
    unsigned* FLG = (unsigned*)alloc(2 * 128 * FLAG_STRIDE * 4);
    float*    H1  = (float*)alloc(32768ull * 4);
    float*    H2  = (float*)alloc(8192ull * 4);
    float*    CTX = (float*)alloc(8192ull * 4);
    float*    C1  = (float*)alloc(16384ull * 4);
    float*    C2  = (float*)alloc(4096ull * 4);

    const size_t A_elems = 32ull * 1664 * 512;  // 27,262,976
    const size_t B_elems = 32ull * 832 * 512;   // 13,631,488
    const size_t L3_elems = 32ull * 208 * 512;  //  3,407,872

    size_t misc_end = off;
    size_t need_f32  = misc_end + (A_elems + B_elems) * 4 + 2048;
    size_t need_bf16 = misc_end + L3_elems * 4 + (A_elems + B_elems) * 2 + 2048;

    const float* enc_out;  // fp32 [6656][512] view of final encoder output
    if (ws_size >= need_f32) {
        float* A = (float*)alloc(A_elems * 4);
        float* B = (float*)alloc(B_elems * 4);
        run_encoder<float>(x, e_fw_Wih, e_fw_Whh, e_fw_b, e_bw_Wih, e_bw_Whh, e_bw_b,
                           p_fw_Wih, p_fw_Whh, p_fw_b, p_bw_Wih, p_bw_Whh, p_bw_b,
                           A, B, HB, FLG, stream);
        enc_out = B;
    } else if (ws_size >= need_bf16) {
        float* CONV = (float*)alloc(L3_elems * 4);
        __hip_bfloat16* A = (__hip_bfloat16*)alloc(A_elems * 2);
        __hip_bfloat16* B = (__hip_bfloat16*)alloc(B_elems * 2);
        run_encoder<__hip_bfloat16>(x, e_fw_Wih, e_fw_Whh, e_fw_b, e_bw_Wih, e_bw_Whh, e_bw_b,
                                    p_fw_Wih, p_fw_Whh, p_fw_b, p_bw_Wih, p_bw_Whh, p_bw_b,
                                    A, B, HB, FLG, stream);
        hipLaunchKernelGGL(bf16_to_f32, dim3((unsigned)(L3_elems / 256)), dim3(256), 0, stream,
                           B, CONV, (int)L3_elems);
        enc_out = CONV;
    } else {
        return;  // workspace too small for any plan
    }

    // ---- key / val projections + decoder precompute ----
    hipLaunchKernelGGL(gemm_bt, dim3(52, 1), dim3(256), 0, stream,
                       enc_out, Wk, bk, KEY, 6656, 128, 512, 512);
    hipLaunchKernelGGL(gemm_bt, dim3(52, 1), dim3(256), 0, stream,
                       enc_out, Wv, bv, VAL, 6656, 128, 512, 512);
    hipLaunchKernelGGL(gemm_bt, dim3(1, 16), dim3(256), 0, stream,
                       emb, d1_Wih, d1_b, TBL, 30, 2048, 256, 384);
    hipLaunchKernelGGL(ctx0_kernel, dim3(16), dim3(256), 0, stream, VAL, CTX);
    hipMemsetAsync(H1, 0, 32768 * 4, stream);
    hipMemsetAsync(H2, 0, 8192 * 4, stream);
    hipMemsetAsync(C1, 0, 16384 * 4, stream);
    hipMemsetAsync(C2, 0, 4096 * 4, stream);

    float* preds = (float*)d_out;
    float* attn0 = (float*)d_out + 192000;

    for (int t = 0; t < 200; t++) {
        float* h1i = H1 + (t & 1) * 16384;
        float* h1o = H1 + ((t + 1) & 1) * 16384;
        float* h2i = H2 + (t & 1) * 4096;
        float* h2o = H2 + ((t + 1) & 1) * 4096;
        float* cxi = CTX + (t & 1) * 4096;
        float* cxo = CTX + ((t + 1) & 1) * 4096;
        hipLaunchKernelGGL(dec_cell1, dim3(64), dim3(256), 0, stream,
                           TBL, y, d1_Wih, d1_Whh, cxi, h1i, h1o, C1, t);
        hipLaunchKernelGGL(dec_cell2, dim3(16), dim3(256), 0, stream,
                           d2_Wih, d2_Whh, d2_b, h1o, h2i, h2o, C2);
        hipLaunchKernelGGL(dec_attend, dim3(32), dim3(256), 0, stream,
                           KEY, VAL, h2o, emb, b_out, cxo, preds, attn0, t);
    }
}